// Round 5
// baseline (2558.667 us; speedup 1.0000x reference)
//
#include <hip/hip_runtime.h>

#define EDIM 1024
#define LNUM 24
#define FDIM 4096
#define NB 256   // persistent blocks (<= 1 per CU easily resident)
#define NT 512   // 8 waves per block; total 2048 waves

__device__ __forceinline__ float wave_sum(float v) {
#pragma unroll
    for (int off = 32; off > 0; off >>= 1) v += __shfl_xor(v, off, 64);
    return v;
}

// Device-wide barrier. cnt starts at 0 each launch (host memsetAsync).
// Monotonic counter; barrier k's increments return values in [k*NB,(k+1)*NB),
// so release target = floor(old/NB)*NB + NB. Relaxed atomics + explicit
// agent-scope fences (release before arrive, acquire after release observed).
__device__ __forceinline__ void gbar(unsigned* cnt) {
    __syncthreads();  // drains each wave's vmcnt -> all block stores at L2; prefetch loads complete (productive BW time)
    if (threadIdx.x == 0) {
        __threadfence();  // agent release (wb L2 dirty lines)
        unsigned old = __hip_atomic_fetch_add(cnt, 1u, __ATOMIC_RELAXED, __HIP_MEMORY_SCOPE_AGENT);
        unsigned target = (old & ~(unsigned)(NB - 1)) + NB;
        int guard = 0;
        while (__hip_atomic_load(cnt, __ATOMIC_RELAXED, __HIP_MEMORY_SCOPE_AGENT) < target) {
            __builtin_amdgcn_s_sleep(2);
            if (++guard > (1 << 24)) break;  // ~1s bailout: fail fast instead of infra hang
        }
        __threadfence();  // agent acquire (inv L1/L2)
    }
    __syncthreads();
}

__device__ __forceinline__ float dot16(const float4& p0, const float4& p1,
                                       const float4& p2, const float4& p3,
                                       const float4& a, const float4& b,
                                       const float4& c, const float4& d) {
    return p0.x * a.x + p0.y * a.y + p0.z * a.z + p0.w * a.w +
           p1.x * b.x + p1.y * b.y + p1.z * b.z + p1.w * b.w +
           p2.x * c.x + p2.y * c.y + p2.z * c.z + p2.w * c.w +
           p3.x * d.x + p3.y * d.y + p3.z * d.z + p3.w * d.w;
}

// 1024-dot with weights already prefetched into registers; operand in LDS.
__device__ __forceinline__ float dot1024_pref(const float4& p0, const float4& p1,
                                              const float4& p2, const float4& p3,
                                              const float* op, int lane) {
    const float4* o = (const float4*)op;
    return wave_sum(dot16(p0, p1, p2, p3, o[lane], o[lane + 64], o[lane + 128], o[lane + 192]));
}

// 1024-dot loading weights from global in-phase.
__device__ __forceinline__ float dot1024_mem(const float* __restrict__ Wrow,
                                             const float* op, int lane) {
    const float4* q = (const float4*)Wrow;
    const float4* o = (const float4*)op;
    return wave_sum(dot16(q[lane], q[lane + 64], q[lane + 128], q[lane + 192],
                          o[lane], o[lane + 64], o[lane + 128], o[lane + 192]));
}

__device__ __forceinline__ float dot512_pref(const float4& p0, const float4& p1,
                                             const float* op, int lane) {
    const float4* o = (const float4*)op;
    float4 a = o[lane], b4 = o[lane + 64];
    float acc = p0.x * a.x + p0.y * a.y + p0.z * a.z + p0.w * a.w +
                p1.x * b4.x + p1.y * b4.y + p1.z * b4.z + p1.w * b4.w;
    return wave_sum(acc);
}

// LayerNorm across 1024 elems, 512 threads each owning float2 at index 2t.
// red = 16-float LDS scratch (must not alias op buffers).
__device__ __forceinline__ float2 block_ln512(float2 xv, const float* __restrict__ wp,
                                              const float* __restrict__ bp,
                                              float* red, int t, int w, int lane) {
    float s = wave_sum(xv.x + xv.y);
    if (lane == 0) red[w] = s;
    __syncthreads();
    float tot = 0.0f;
#pragma unroll
    for (int i = 0; i < 8; ++i) tot += red[i];
    const float mu = tot * (1.0f / 1024.0f);
    const float dx = xv.x - mu, dy = xv.y - mu;
    float s2 = wave_sum(dx * dx + dy * dy);
    __syncthreads();  // all reads of pass-1 red done before pass-2 writes
    if (lane == 0) red[w] = s2;
    __syncthreads();
    float tot2 = 0.0f;
#pragma unroll
    for (int i = 0; i < 8; ++i) tot2 += red[i];
    const float inv = rsqrtf(tot2 * (1.0f / 1024.0f) + 1e-5f);
    const float2 wv = ((const float2*)wp)[t];
    const float2 bv = ((const float2*)bp)[t];
    return make_float2(dx * inv * wv.x + bv.x, dy * inv * wv.y + bv.y);
}

__global__ __launch_bounds__(NT, 4) void rwkv_persistent(
    const float* __restrict__ x_in, const float* __restrict__ state,
    const float* __restrict__ ln1w, const float* __restrict__ ln1b,
    const float* __restrict__ ln2w, const float* __restrict__ ln2b,
    const float* __restrict__ td, const float* __restrict__ tf,
    const float* __restrict__ key, const float* __restrict__ ow,
    const float* __restrict__ mixk, const float* __restrict__ mixv,
    const float* __restrict__ mixr, const float* __restrict__ mixkf,
    const float* __restrict__ mixrf, const float* __restrict__ kffn,
    const float* __restrict__ rffn, const float* __restrict__ vffn,
    float* __restrict__ out, float* __restrict__ ws, unsigned* __restrict__ cnt) {
    __shared__ float smem[FDIM + 64];
    float* red = smem + FDIM;  // 16 floats of reduce scratch

    float* xbuf = ws;             // [1024] residual stream
    float* sxbuf = ws + 1024;     // [1024]
    float* kbuf = ws + 2048;      // [1024]
    float* vbuf = ws + 3072;      // [1024]
    float* rbuf = ws + 4096;      // [1024]
    float* kfbuf = ws + 5120;     // [4096]
    float* rdiv = ws + 9216;      // [1024]

    float* sa_out = out + EDIM;
    float* sb_out = sa_out + LNUM * EDIM;
    float* sc_out = sb_out + LNUM * EDIM;
    float* sd_out = sc_out + LNUM * EDIM;

    const int t = threadIdx.x;
    const int b = blockIdx.x;
    const int w = t >> 6;
    const int lane = t & 63;
    const int gw = (b << 3) + w;  // global wave id, 0..2047

    // Prologue: prefetch layer-0 phase-A row gw (rows 0..2047 = k and v mats).
    float4 pA0, pA1, pA2, pA3;
    {
        const float4* q = (const float4*)(key + ((size_t)gw << 10));
        pA0 = q[lane]; pA1 = q[lane + 64]; pA2 = q[lane + 128]; pA3 = q[lane + 192];
    }

    for (int l = 0; l < LNUM; ++l) {
        const float* cx = (l == 0) ? x_in : xbuf;
        const float* keyl = key + (size_t)l * 3 * EDIM * EDIM;
        const float* owl = ow + (size_t)l * EDIM * EDIM;
        const float* kfl = kffn + (size_t)l * FDIM * EDIM;
        const float* rfl = rffn + (size_t)l * EDIM * EDIM;
        const float* vfl = vffn + (size_t)l * EDIM * FDIM;
        const int le = l * EDIM;

        // ================= Phase A: LN1 + k/v/r matvecs =================
        {
            const float2 xv = ((const float2*)cx)[t];
            const float2 xn = block_ln512(xv, ln1w + le, ln1b + le, red, t, w, lane);
            if (b == 0) ((float2*)(sa_out + le))[t] = xn;  // sa = ln1 output
            const float2 sav = ((const float2*)(state + le))[t];
            const float2 mk = ((const float2*)(mixk + le))[t];
            const float2 mv = ((const float2*)(mixv + le))[t];
            const float2 mr = ((const float2*)(mixr + le))[t];
            ((float2*)smem)[t] = make_float2(xn.x + mk.x * sav.x, xn.y + mk.y * sav.y);
            ((float2*)(smem + 1024))[t] = make_float2(xn.x + mv.x * sav.x, xn.y + mv.y * sav.y);
            ((float2*)(smem + 2048))[t] = make_float2(xn.x + mr.x * sav.x, xn.y + mr.y * sav.y);
            __syncthreads();
            // first row (prefetched): gw<1024 -> k-mat row gw; else v-mat row gw-1024
            const int mat = gw >> 10;  // 0 or 1
            const float d1 = dot1024_pref(pA0, pA1, pA2, pA3, smem + (mat << 10), lane);
            if (lane == 0) {
                if (mat == 0) kbuf[gw] = expf(d1);
                else          vbuf[gw - 1024] = d1;
            }
            // second row (in-phase): rows 2048..3071 = r-mat
            if (gw < 1024) {
                const float d2 = dot1024_mem(keyl + ((size_t)(gw + 2048) << 10), smem + 2048, lane);
                if (lane == 0) rbuf[gw] = expf(d2) + 1.0f;
            }
        }
        // prefetch phase-B half-row and BOTH phase-C kfw rows before the barrier
        float4 pB0, pB1;
        {
            const float4* qB = (const float4*)(owl + (((b << 2) + (w >> 1)) << 10) + ((w & 1) << 9));
            pB0 = qB[lane]; pB1 = qB[lane + 64];
        }
        float4 pC0, pC1, pC2, pC3, pC4, pC5, pC6, pC7;
        {
            const float4* q1 = (const float4*)(kfl + ((size_t)gw << 10));
            pC0 = q1[lane]; pC1 = q1[lane + 64]; pC2 = q1[lane + 128]; pC3 = q1[lane + 192];
            const float4* q2 = (const float4*)(kfl + ((size_t)(gw + 2048) << 10));
            pC4 = q2[lane]; pC5 = q2[lane + 64]; pC6 = q2[lane + 128]; pC7 = q2[lane + 192];
        }
        gbar(cnt);

        // ================= Phase B: WKV + ow matvec + residual =================
        {
            const float2 k2 = ((const float2*)kbuf)[t];
            const float2 v2 = ((const float2*)vbuf)[t];
            const float2 r2 = ((const float2*)rbuf)[t];
            const float2 tf2 = ((const float2*)(tf + le))[t];
            const float2 sb2 = ((const float2*)(state + 1 * LNUM * EDIM + le))[t];
            const float2 sc2 = ((const float2*)(state + 2 * LNUM * EDIM + le))[t];
            const float g0 = (sb2.x + tf2.x * k2.x * v2.x) / (sc2.x * r2.x + tf2.x * k2.x * r2.x);
            const float g1 = (sb2.y + tf2.y * k2.y * v2.y) / (sc2.y * r2.y + tf2.y * k2.y * r2.y);
            ((float2*)smem)[t] = make_float2(g0, g1);
            if (b == 0) {  // state updates sb', sc'
                const float2 td2 = ((const float2*)(td + le))[t];
                ((float2*)(sb_out + le))[t] =
                    make_float2(sb2.x * td2.x + k2.x * v2.x, sb2.y * td2.y + k2.y * v2.y);
                ((float2*)(sc_out + le))[t] =
                    make_float2(sc2.x * td2.x + k2.x, sc2.y * td2.y + k2.y);
            }
            __syncthreads();
            const float pd = dot512_pref(pB0, pB1, smem + ((w & 1) << 9), lane);
            if (lane == 0) red[w] = pd;
            __syncthreads();
            if (t < 4) {
                const int r = (b << 2) + t;
                sxbuf[r] = cx[r] + red[2 * t] + red[2 * t + 1];
            }
        }
        gbar(cnt);

        // ================= Phase C: LN2 + kfw/rfw matvecs =================
        {
            const float2 sxv = ((const float2*)sxbuf)[t];
            const float2 x2 = block_ln512(sxv, ln2w + le, ln2b + le, red, t, w, lane);
            if (b == 0) ((float2*)(sd_out + le))[t] = x2;  // sd = ln2 output
            const float2 sdv = ((const float2*)(state + 3 * LNUM * EDIM + le))[t];
            const float2 mkf = ((const float2*)(mixkf + le))[t];
            const float2 mrf = ((const float2*)(mixrf + le))[t];
            ((float2*)smem)[t] = make_float2(x2.x + mkf.x * sdv.x, x2.y + mkf.y * sdv.y);
            ((float2*)(smem + 1024))[t] = make_float2(x2.x + mrf.x * sdv.x, x2.y + mrf.y * sdv.y);
            __syncthreads();
            const float d1 = dot1024_pref(pC0, pC1, pC2, pC3, smem, lane);
            if (lane == 0) {
                const float rl = fmaxf(d1, 0.0f);
                kfbuf[gw] = rl * rl;
            }
            const float d2 = dot1024_pref(pC4, pC5, pC6, pC7, smem, lane);
            if (lane == 0) {
                const float rl = fmaxf(d2, 0.0f);
                kfbuf[gw + 2048] = rl * rl;
            }
            if (gw < 1024) {  // rfw rows, in-phase
                const float d3 = dot1024_mem(rfl + ((size_t)gw << 10), smem + 1024, lane);
                if (lane == 0) rdiv[gw] = 1.0f / (1.0f + expf(d3));
            }
        }
        // prefetch both phase-D chunk-units before the barrier
        const int drow = (b << 2) + (w >> 2);
        const int dch = w & 3;
        float4 pD0, pD1, pD2, pD3, pD4, pD5, pD6, pD7;
        {
            const float4* q1 = (const float4*)(vfl + ((size_t)drow << 12) + (dch << 10));
            pD0 = q1[lane]; pD1 = q1[lane + 64]; pD2 = q1[lane + 128]; pD3 = q1[lane + 192];
            const float4* q2 = (const float4*)(vfl + ((size_t)(drow + 2) << 12) + (dch << 10));
            pD4 = q2[lane]; pD5 = q2[lane + 64]; pD6 = q2[lane + 128]; pD7 = q2[lane + 192];
        }
        gbar(cnt);

        // ================= Phase D: vfw matvec + gated residual =================
        {
            // stage kf[4096] into LDS (L2-hot)
            ((float4*)smem)[t] = ((const float4*)kfbuf)[t];
            ((float4*)smem)[t + 512] = ((const float4*)kfbuf)[t + 512];
            __syncthreads();
            const float pd0 = dot1024_pref(pD0, pD1, pD2, pD3, smem + (dch << 10), lane);
            const float pd1 = dot1024_pref(pD4, pD5, pD6, pD7, smem + (dch << 10), lane);
            if (lane == 0) { red[w] = pd0; red[w + 8] = pd1; }  // red[u]: row 4b+(u>>2), chunk u&3
            __syncthreads();
            if (t < 4) {
                const int r = (b << 2) + t;
                const float dsum = red[4 * t] + red[4 * t + 1] + red[4 * t + 2] + red[4 * t + 3];
                const float val = sxbuf[r] + dsum * rdiv[r];
                if (l == LNUM - 1) out[r] = val;
                else xbuf[r] = val;
            }
        }
        if (l < LNUM - 1) {
            // prefetch next layer's phase-A row across the D->A' barrier
            const float4* qA = (const float4*)(key + (size_t)(l + 1) * 3 * EDIM * EDIM + ((size_t)gw << 10));
            pA0 = qA[lane]; pA1 = qA[lane + 64]; pA2 = qA[lane + 128]; pA3 = qA[lane + 192];
            gbar(cnt);
        }
    }
}

extern "C" void kernel_launch(void* const* d_in, const int* in_sizes, int n_in,
                              void* d_out, int out_size, void* d_ws, size_t ws_size,
                              hipStream_t stream) {
    const float* x_in = (const float*)d_in[0];
    const float* state = (const float*)d_in[1];
    const float* ln1w = (const float*)d_in[2];
    const float* ln1b = (const float*)d_in[3];
    const float* ln2w = (const float*)d_in[4];
    const float* ln2b = (const float*)d_in[5];
    const float* td = (const float*)d_in[6];
    const float* tf = (const float*)d_in[7];
    const float* key = (const float*)d_in[8];    // [L,3,E,E]
    const float* ow = (const float*)d_in[9];     // [L,E,E]
    const float* mixk = (const float*)d_in[10];
    const float* mixv = (const float*)d_in[11];
    const float* mixr = (const float*)d_in[12];
    const float* mixkf = (const float*)d_in[13];
    const float* mixrf = (const float*)d_in[14];
    const float* kffn = (const float*)d_in[15];  // [L,F,E]
    const float* rffn = (const float*)d_in[16];  // [L,E,E]
    const float* vffn = (const float*)d_in[17];  // [L,E,F]

    float* out = (float*)d_out;
    float* ws = (float*)d_ws;
    unsigned* cnt = (unsigned*)((char*)d_ws + 64 * 1024);  // past the 40 KB vector region

    hipMemsetAsync(cnt, 0, sizeof(unsigned), stream);  // deterministic barrier state per replay
    rwkv_persistent<<<NB, NT, 0, stream>>>(x_in, state, ln1w, ln1b, ln2w, ln2b, td, tf,
                                           key, ow, mixk, mixv, mixr, mixkf, mixrf,
                                           kffn, rffn, vffn, out, ws, cnt);
}

// Round 6
// 1847.450 us; speedup vs baseline: 1.3850x; 1.3850x over previous
//
#include <hip/hip_runtime.h>

#define EDIM 1024
#define LNUM 24
#define FDIM 4096
#define NB 256   // persistent blocks, 1 per CU
#define NT 512   // 8 waves per block

__device__ __forceinline__ float wave_sum(float v) {
#pragma unroll
    for (int off = 32; off > 0; off >>= 1) v += __shfl_xor(v, off, 64);
    return v;
}

// ---- Two-level (XCD-grouped) device barrier, split into arrive/wait so that
// prefetch loads can be issued in between (they stream while thread 0 polls).
// grp: 8 counters padded to 64B lines; gcnt: global group counter; rel: epoch.
// All zeroed at launch. Monotonic: barrier bi's group increments return
// [32*bi, 32*bi+32), last has low5==31; gcnt returns [8*bi, 8*bi+8), last
// low3==7 -> stores rel=bi+1.
__device__ __forceinline__ void gbar_arrive(unsigned* grp, unsigned* gcnt,
                                            unsigned* rel, unsigned bi) {
    __syncthreads();  // all block stores drained to L2 (vmcnt0)
    if (threadIdx.x == 0) {
        __threadfence();  // agent release: wb L2 so other XCDs can see our stores
        unsigned o = __hip_atomic_fetch_add(&grp[(blockIdx.x & 7) << 4], 1u,
                                            __ATOMIC_RELAXED, __HIP_MEMORY_SCOPE_AGENT);
        if ((o & 31u) == 31u) {  // last of 32 in this group
            unsigned go = __hip_atomic_fetch_add(gcnt, 1u, __ATOMIC_RELAXED,
                                                 __HIP_MEMORY_SCOPE_AGENT);
            if ((go & 7u) == 7u)  // last group
                __hip_atomic_store(rel, bi + 1u, __ATOMIC_RELAXED,
                                   __HIP_MEMORY_SCOPE_AGENT);
        }
    }
}

__device__ __forceinline__ void gbar_wait(unsigned* rel, unsigned bi) {
    if (threadIdx.x == 0) {
        int guard = 0;
        while (__hip_atomic_load(rel, __ATOMIC_RELAXED, __HIP_MEMORY_SCOPE_AGENT) <
               bi + 1u) {
            __builtin_amdgcn_s_sleep(8);            // ~512 cy between polls
            if (++guard > (1 << 20)) break;          // fail-fast bailout
        }
        __threadfence();  // agent acquire: inv L1/L2 before reading others' data
    }
    __syncthreads();
}

__device__ __forceinline__ float dot16(const float4& p0, const float4& p1,
                                       const float4& p2, const float4& p3,
                                       const float4& a, const float4& b,
                                       const float4& c, const float4& d) {
    return p0.x * a.x + p0.y * a.y + p0.z * a.z + p0.w * a.w +
           p1.x * b.x + p1.y * b.y + p1.z * b.z + p1.w * b.w +
           p2.x * c.x + p2.y * c.y + p2.z * c.z + p2.w * c.w +
           p3.x * d.x + p3.y * d.y + p3.z * d.z + p3.w * d.w;
}

__device__ __forceinline__ float dot1024_pref(const float4& p0, const float4& p1,
                                              const float4& p2, const float4& p3,
                                              const float* op, int lane) {
    const float4* o = (const float4*)op;
    return wave_sum(dot16(p0, p1, p2, p3, o[lane], o[lane + 64], o[lane + 128],
                          o[lane + 192]));
}

__device__ __forceinline__ float dot1024_mem(const float* __restrict__ Wrow,
                                             const float* op, int lane) {
    const float4* q = (const float4*)Wrow;
    const float4* o = (const float4*)op;
    return wave_sum(dot16(q[lane], q[lane + 64], q[lane + 128], q[lane + 192],
                          o[lane], o[lane + 64], o[lane + 128], o[lane + 192]));
}

__device__ __forceinline__ float dot512_pref(const float4& p0, const float4& p1,
                                             const float* op, int lane) {
    const float4* o = (const float4*)op;
    float4 a = o[lane], b4 = o[lane + 64];
    float acc = p0.x * a.x + p0.y * a.y + p0.z * a.z + p0.w * a.w +
                p1.x * b4.x + p1.y * b4.y + p1.z * b4.z + p1.w * b4.w;
    return wave_sum(acc);
}

// LayerNorm across 1024 elems, 512 threads each owning float2 at index 2t.
__device__ __forceinline__ float2 block_ln512(float2 xv, const float* __restrict__ wp,
                                              const float* __restrict__ bp,
                                              float* red, int t, int w, int lane) {
    float s = wave_sum(xv.x + xv.y);
    if (lane == 0) red[w] = s;
    __syncthreads();
    float tot = 0.0f;
#pragma unroll
    for (int i = 0; i < 8; ++i) tot += red[i];
    const float mu = tot * (1.0f / 1024.0f);
    const float dx = xv.x - mu, dy = xv.y - mu;
    float s2 = wave_sum(dx * dx + dy * dy);
    __syncthreads();
    if (lane == 0) red[w] = s2;
    __syncthreads();
    float tot2 = 0.0f;
#pragma unroll
    for (int i = 0; i < 8; ++i) tot2 += red[i];
    const float inv = rsqrtf(tot2 * (1.0f / 1024.0f) + 1e-5f);
    const float2 wv = ((const float2*)wp)[t];
    const float2 bv = ((const float2*)bp)[t];
    return make_float2(dx * inv * wv.x + bv.x, dy * inv * wv.y + bv.y);
}

__global__ __launch_bounds__(NT, 2) void rwkv_persistent(
    const float* __restrict__ x_in, const float* __restrict__ state,
    const float* __restrict__ ln1w, const float* __restrict__ ln1b,
    const float* __restrict__ ln2w, const float* __restrict__ ln2b,
    const float* __restrict__ td, const float* __restrict__ tf,
    const float* __restrict__ key, const float* __restrict__ ow,
    const float* __restrict__ mixk, const float* __restrict__ mixv,
    const float* __restrict__ mixr, const float* __restrict__ mixkf,
    const float* __restrict__ mixrf, const float* __restrict__ kffn,
    const float* __restrict__ rffn, const float* __restrict__ vffn,
    float* __restrict__ out, float* __restrict__ ws, unsigned* __restrict__ grp,
    unsigned* __restrict__ gcnt, unsigned* __restrict__ rel) {
    __shared__ float smem[FDIM + 64];
    float* red = smem + FDIM;

    float* xbuf = ws;           // [1024] residual stream
    float* sxbuf = ws + 1024;   // [1024]
    float* kbuf = ws + 2048;    // [1024]
    float* vbuf = ws + 3072;    // [1024]
    float* rbuf = ws + 4096;    // [1024]
    float* kfbuf = ws + 5120;   // [4096]
    float* rdiv = ws + 9216;    // [1024]

    float* sa_out = out + EDIM;
    float* sb_out = sa_out + LNUM * EDIM;
    float* sc_out = sb_out + LNUM * EDIM;
    float* sd_out = sc_out + LNUM * EDIM;

    const int t = threadIdx.x;
    const int b = blockIdx.x;
    const int w = t >> 6;
    const int lane = t & 63;
    const int gw = (b << 3) + w;  // 0..2047
    unsigned bi = 0;

    // Prologue: prefetch layer-0 phase-A row gw (rows 0..2047 = k-mat, v-mat).
    float4 pA0, pA1, pA2, pA3;
    {
        const float4* q = (const float4*)(key + ((size_t)gw << 10));
        pA0 = q[lane]; pA1 = q[lane + 64]; pA2 = q[lane + 128]; pA3 = q[lane + 192];
    }

    for (int l = 0; l < LNUM; ++l) {
        const float* cx = (l == 0) ? x_in : xbuf;
        const float* keyl = key + (size_t)l * 3 * EDIM * EDIM;
        const float* owl = ow + (size_t)l * EDIM * EDIM;
        const float* kfl = kffn + (size_t)l * FDIM * EDIM;
        const float* rfl = rffn + (size_t)l * EDIM * EDIM;
        const float* vfl = vffn + (size_t)l * EDIM * FDIM;
        const int le = l * EDIM;

        // ================= Phase A: LN1 + k/v/r matvecs =================
        {
            const float2 xv = ((const float2*)cx)[t];
            const float2 xn = block_ln512(xv, ln1w + le, ln1b + le, red, t, w, lane);
            if (b == 0) ((float2*)(sa_out + le))[t] = xn;
            const float2 sav = ((const float2*)(state + le))[t];
            const float2 mk = ((const float2*)(mixk + le))[t];
            const float2 mv = ((const float2*)(mixv + le))[t];
            const float2 mr = ((const float2*)(mixr + le))[t];
            ((float2*)smem)[t] = make_float2(xn.x + mk.x * sav.x, xn.y + mk.y * sav.y);
            ((float2*)(smem + 1024))[t] = make_float2(xn.x + mv.x * sav.x, xn.y + mv.y * sav.y);
            ((float2*)(smem + 2048))[t] = make_float2(xn.x + mr.x * sav.x, xn.y + mr.y * sav.y);
            __syncthreads();
            const int mat = gw >> 10;  // 0 -> k row, 1 -> v row
            const float d1 = dot1024_pref(pA0, pA1, pA2, pA3, smem + (mat << 10), lane);
            if (lane == 0) {
                if (mat == 0) kbuf[gw] = expf(d1);
                else          vbuf[gw - 1024] = d1;
            }
            if (gw < 1024) {  // r-mat rows, loaded in-phase (mid-phase BW)
                const float d2 = dot1024_mem(keyl + ((size_t)(gw + 2048) << 10),
                                             smem + 2048, lane);
                if (lane == 0) rbuf[gw] = expf(d2) + 1.0f;
            }
        }
        gbar_arrive(grp, gcnt, rel, bi);
        // -- window A->B: issue pB (ow half-row) + pC1 (kfw row gw); streams during poll
        float4 pB0, pB1, pC10, pC11, pC12, pC13;
        {
            const float4* qB = (const float4*)(owl + (((b << 2) + (w >> 1)) << 10) +
                                               ((w & 1) << 9));
            pB0 = qB[lane]; pB1 = qB[lane + 64];
            const float4* q1 = (const float4*)(kfl + ((size_t)gw << 10));
            pC10 = q1[lane]; pC11 = q1[lane + 64]; pC12 = q1[lane + 128]; pC13 = q1[lane + 192];
        }
        gbar_wait(rel, bi); ++bi;

        // ================= Phase B: WKV + ow matvec + residual =================
        {
            const float2 k2 = ((const float2*)kbuf)[t];
            const float2 v2 = ((const float2*)vbuf)[t];
            const float2 r2 = ((const float2*)rbuf)[t];
            const float2 tf2 = ((const float2*)(tf + le))[t];
            const float2 sb2 = ((const float2*)(state + 1 * LNUM * EDIM + le))[t];
            const float2 sc2 = ((const float2*)(state + 2 * LNUM * EDIM + le))[t];
            const float g0 = (sb2.x + tf2.x * k2.x * v2.x) / (sc2.x * r2.x + tf2.x * k2.x * r2.x);
            const float g1 = (sb2.y + tf2.y * k2.y * v2.y) / (sc2.y * r2.y + tf2.y * k2.y * r2.y);
            ((float2*)smem)[t] = make_float2(g0, g1);
            if (b == 0) {
                const float2 td2 = ((const float2*)(td + le))[t];
                ((float2*)(sb_out + le))[t] =
                    make_float2(sb2.x * td2.x + k2.x * v2.x, sb2.y * td2.y + k2.y * v2.y);
                ((float2*)(sc_out + le))[t] =
                    make_float2(sc2.x * td2.x + k2.x, sc2.y * td2.y + k2.y);
            }
            __syncthreads();
            const float pd = dot512_pref(pB0, pB1, smem + ((w & 1) << 9), lane);
            if (lane == 0) red[w] = pd;
            __syncthreads();
            if (t < 4) {
                const int r = (b << 2) + t;
                sxbuf[r] = cx[r] + red[2 * t] + red[2 * t + 1];
            }
        }
        gbar_arrive(grp, gcnt, rel, bi);
        // -- window B->C: issue pC2 (kfw row gw+2048)
        float4 pC20, pC21, pC22, pC23;
        {
            const float4* q2 = (const float4*)(kfl + ((size_t)(gw + 2048) << 10));
            pC20 = q2[lane]; pC21 = q2[lane + 64]; pC22 = q2[lane + 128]; pC23 = q2[lane + 192];
        }
        gbar_wait(rel, bi); ++bi;

        // ================= Phase C: LN2 + kfw/rfw matvecs =================
        {
            const float2 sxv = ((const float2*)sxbuf)[t];
            const float2 x2 = block_ln512(sxv, ln2w + le, ln2b + le, red, t, w, lane);
            if (b == 0) ((float2*)(sd_out + le))[t] = x2;
            const float2 sdv = ((const float2*)(state + 3 * LNUM * EDIM + le))[t];
            const float2 mkf = ((const float2*)(mixkf + le))[t];
            const float2 mrf = ((const float2*)(mixrf + le))[t];
            ((float2*)smem)[t] = make_float2(x2.x + mkf.x * sdv.x, x2.y + mkf.y * sdv.y);
            ((float2*)(smem + 1024))[t] = make_float2(x2.x + mrf.x * sdv.x, x2.y + mrf.y * sdv.y);
            __syncthreads();
            const float d1 = dot1024_pref(pC10, pC11, pC12, pC13, smem, lane);
            if (lane == 0) { const float rl = fmaxf(d1, 0.0f); kfbuf[gw] = rl * rl; }
            const float d2 = dot1024_pref(pC20, pC21, pC22, pC23, smem, lane);
            if (lane == 0) { const float rl = fmaxf(d2, 0.0f); kfbuf[gw + 2048] = rl * rl; }
            if (gw < 1024) {  // rfw rows in-phase
                const float d3 = dot1024_mem(rfl + ((size_t)gw << 10), smem + 1024, lane);
                if (lane == 0) rdiv[gw] = 1.0f / (1.0f + expf(d3));
            }
        }
        gbar_arrive(grp, gcnt, rel, bi);
        // -- window C->D: issue both vfw chunk-units
        const int drow = (b << 2) + (w >> 2);
        const int dch = w & 3;
        float4 pD0, pD1, pD2, pD3, pD4, pD5, pD6, pD7;
        {
            const float4* q1 = (const float4*)(vfl + ((size_t)drow << 12) + (dch << 10));
            pD0 = q1[lane]; pD1 = q1[lane + 64]; pD2 = q1[lane + 128]; pD3 = q1[lane + 192];
            const float4* q2 = (const float4*)(vfl + ((size_t)(drow + 2) << 12) + (dch << 10));
            pD4 = q2[lane]; pD5 = q2[lane + 64]; pD6 = q2[lane + 128]; pD7 = q2[lane + 192];
        }
        gbar_wait(rel, bi); ++bi;

        // ================= Phase D: vfw matvec + gated residual =================
        {
            ((float4*)smem)[t] = ((const float4*)kfbuf)[t];
            ((float4*)smem)[t + 512] = ((const float4*)kfbuf)[t + 512];
            __syncthreads();
            const float pd0 = dot1024_pref(pD0, pD1, pD2, pD3, smem + (dch << 10), lane);
            const float pd1 = dot1024_pref(pD4, pD5, pD6, pD7, smem + (dch << 10), lane);
            if (lane == 0) { red[w] = pd0; red[w + 8] = pd1; }
            __syncthreads();
            if (t < 4) {
                const int r = (b << 2) + t;
                const float dsum = red[4 * t] + red[4 * t + 1] + red[4 * t + 2] + red[4 * t + 3];
                const float val = sxbuf[r] + dsum * rdiv[r];
                if (l == LNUM - 1) out[r] = val;
                else xbuf[r] = val;
            }
        }
        if (l < LNUM - 1) {
            gbar_arrive(grp, gcnt, rel, bi);
            // -- window D->A': prefetch next layer's phase-A row
            const float4* qA = (const float4*)(key + (size_t)(l + 1) * 3 * EDIM * EDIM +
                                               ((size_t)gw << 10));
            pA0 = qA[lane]; pA1 = qA[lane + 64]; pA2 = qA[lane + 128]; pA3 = qA[lane + 192];
            gbar_wait(rel, bi); ++bi;
        }
    }
}

extern "C" void kernel_launch(void* const* d_in, const int* in_sizes, int n_in,
                              void* d_out, int out_size, void* d_ws, size_t ws_size,
                              hipStream_t stream) {
    const float* x_in = (const float*)d_in[0];
    const float* state = (const float*)d_in[1];
    const float* ln1w = (const float*)d_in[2];
    const float* ln1b = (const float*)d_in[3];
    const float* ln2w = (const float*)d_in[4];
    const float* ln2b = (const float*)d_in[5];
    const float* td = (const float*)d_in[6];
    const float* tf = (const float*)d_in[7];
    const float* key = (const float*)d_in[8];
    const float* ow = (const float*)d_in[9];
    const float* mixk = (const float*)d_in[10];
    const float* mixv = (const float*)d_in[11];
    const float* mixr = (const float*)d_in[12];
    const float* mixkf = (const float*)d_in[13];
    const float* mixrf = (const float*)d_in[14];
    const float* kffn = (const float*)d_in[15];
    const float* rffn = (const float*)d_in[16];
    const float* vffn = (const float*)d_in[17];

    float* out = (float*)d_out;
    float* ws = (float*)d_ws;

    // Barrier state at 48 KB (vector region ends at 40 KB): 8 padded group
    // counters (64B each), then gcnt, then rel on separate lines.
    unsigned* bar = (unsigned*)((char*)d_ws + 48 * 1024);
    unsigned* grp = bar;                 // grp[g<<4], g=0..7 (512 B)
    unsigned* gcnt = bar + 256;          // +1024 B
    unsigned* rel = bar + 272;           // +1088 B

    hipMemsetAsync(bar, 0, 2048, stream);  // deterministic per replay
    rwkv_persistent<<<NB, NT, 0, stream>>>(x_in, state, ln1w, ln1b, ln2w, ln2b, td, tf,
                                           key, ow, mixk, mixv, mixr, mixkf, mixrf,
                                           kffn, rffn, vffn, out, ws, grp, gcnt, rel);
}

// Round 7
// 605.232 us; speedup vs baseline: 4.2276x; 3.0525x over previous
//
#include <hip/hip_runtime.h>

#define EDIM 1024
#define LNUM 24
#define FDIM 4096
#define NB 256   // persistent blocks, 1 per CU
#define NT 512   // 8 waves per block

__device__ __forceinline__ float wave_sum(float v) {
#pragma unroll
    for (int off = 32; off > 0; off >>= 1) v += __shfl_xor(v, off, 64);
    return v;
}

// ---- Coherent (MALL-visible, L1/L2-bypassing) accessors for cross-block data.
// No __threadfence anywhere: agent-scope relaxed atomics lower to sc1 accesses
// that complete at the coherence point; __syncthreads' vmcnt drain orders them
// before the arrival atomic. Avoids buffer_wbl2/buffer_inv full-L2 scans.
__device__ __forceinline__ float2 cload2(const float* p) {
    double d = __hip_atomic_load((const double*)p, __ATOMIC_RELAXED,
                                 __HIP_MEMORY_SCOPE_AGENT);
    float2 r;
    __builtin_memcpy(&r, &d, 8);
    return r;
}
__device__ __forceinline__ float cload1(const float* p) {
    return __hip_atomic_load(p, __ATOMIC_RELAXED, __HIP_MEMORY_SCOPE_AGENT);
}
__device__ __forceinline__ void cstore1(float* p, float v) {
    __hip_atomic_store(p, v, __ATOMIC_RELAXED, __HIP_MEMORY_SCOPE_AGENT);
}

// ---- Two-level device barrier (8 XCD-group counters -> global -> release),
// fence-free, split into arrive/wait so prefetch loads stream during the poll.
__device__ __forceinline__ void gbar_arrive(unsigned* grp, unsigned* gcnt,
                                            unsigned* rel, unsigned bi) {
    __syncthreads();  // drains vmcnt: this block's coherent stores are at MALL
    if (threadIdx.x == 0) {
        unsigned o = __hip_atomic_fetch_add(&grp[(blockIdx.x & 7) << 4], 1u,
                                            __ATOMIC_RELAXED, __HIP_MEMORY_SCOPE_AGENT);
        if ((o & 31u) == 31u) {  // last of 32 in group
            unsigned go = __hip_atomic_fetch_add(gcnt, 1u, __ATOMIC_RELAXED,
                                                 __HIP_MEMORY_SCOPE_AGENT);
            if ((go & 7u) == 7u)  // last group
                __hip_atomic_store(rel, bi + 1u, __ATOMIC_RELAXED,
                                   __HIP_MEMORY_SCOPE_AGENT);
        }
    }
}

__device__ __forceinline__ void gbar_wait(unsigned* rel, unsigned bi) {
    if (threadIdx.x == 0) {
        int guard = 0;
        while (__hip_atomic_load(rel, __ATOMIC_RELAXED, __HIP_MEMORY_SCOPE_AGENT) <
               bi + 1u) {
            __builtin_amdgcn_s_sleep(1);
            if (++guard > (1 << 20)) break;  // fail-fast bailout
        }
    }
    __syncthreads();
}

__device__ __forceinline__ float dot16(const float4& p0, const float4& p1,
                                       const float4& p2, const float4& p3,
                                       const float4& a, const float4& b,
                                       const float4& c, const float4& d) {
    return p0.x * a.x + p0.y * a.y + p0.z * a.z + p0.w * a.w +
           p1.x * b.x + p1.y * b.y + p1.z * b.z + p1.w * b.w +
           p2.x * c.x + p2.y * c.y + p2.z * c.z + p2.w * c.w +
           p3.x * d.x + p3.y * d.y + p3.z * d.z + p3.w * d.w;
}

__device__ __forceinline__ float dot1024_pref(const float4& p0, const float4& p1,
                                              const float4& p2, const float4& p3,
                                              const float* op, int lane) {
    const float4* o = (const float4*)op;
    return wave_sum(dot16(p0, p1, p2, p3, o[lane], o[lane + 64], o[lane + 128],
                          o[lane + 192]));
}

// half-row (512) dot with weights loaded in-phase from global.
__device__ __forceinline__ float dot512_mem(const float* __restrict__ Wrow,
                                            const float* op, int lane) {
    const float4* q = (const float4*)Wrow;
    const float4* o = (const float4*)op;
    const float4 a = q[lane], b = q[lane + 64];
    const float4 oa = o[lane], ob = o[lane + 64];
    return wave_sum(a.x * oa.x + a.y * oa.y + a.z * oa.z + a.w * oa.w +
                    b.x * ob.x + b.y * ob.y + b.z * ob.z + b.w * ob.w);
}

__device__ __forceinline__ float dot512_pref(const float4& p0, const float4& p1,
                                             const float* op, int lane) {
    const float4* o = (const float4*)op;
    const float4 a = o[lane], b4 = o[lane + 64];
    return wave_sum(p0.x * a.x + p0.y * a.y + p0.z * a.z + p0.w * a.w +
                    p1.x * b4.x + p1.y * b4.y + p1.z * b4.z + p1.w * b4.w);
}

__global__ __launch_bounds__(NT, 2) void rwkv_persistent(
    const float* __restrict__ x_in, const float* __restrict__ state,
    const float* __restrict__ ln1w, const float* __restrict__ ln1b,
    const float* __restrict__ ln2w, const float* __restrict__ ln2b,
    const float* __restrict__ td, const float* __restrict__ tf,
    const float* __restrict__ key, const float* __restrict__ ow,
    const float* __restrict__ mixk, const float* __restrict__ mixv,
    const float* __restrict__ mixr, const float* __restrict__ mixkf,
    const float* __restrict__ mixrf, const float* __restrict__ kffn,
    const float* __restrict__ rffn, const float* __restrict__ vffn,
    float* __restrict__ out, float* __restrict__ ws, unsigned* __restrict__ grp,
    unsigned* __restrict__ gcnt, unsigned* __restrict__ rel) {
    __shared__ float smem[FDIM + 32];
    float* red = smem + FDIM;  // 32 floats: [0..7]=s/partials, [8..15]=s2/pd1, [16..23]=half-row partials

    float* xbuf = ws;           // [1024] residual stream          (coherent)
    float* sxbuf = ws + 1024;   // [1024]                          (coherent)
    float* kbuf = ws + 2048;    // [1024]                          (coherent)
    float* vbuf = ws + 3072;    // [1024]                          (coherent)
    float* rbuf = ws + 4096;    // [1024]                          (coherent)
    float* kfbuf = ws + 5120;   // [4096]                          (coherent)
    float* rdiv = ws + 9216;    // [1024]                          (coherent)

    float* sa_out = out + EDIM;
    float* sb_out = sa_out + LNUM * EDIM;
    float* sc_out = sb_out + LNUM * EDIM;
    float* sd_out = sc_out + LNUM * EDIM;

    const int t = threadIdx.x;
    const int b = blockIdx.x;
    const int w = t >> 6;
    const int lane = t & 63;
    const int gw = (b << 3) + w;  // 0..2047
    unsigned bi = 0;

    // Prologue: prefetch layer-0 phase-A row gw (rows 0..2047 = k-mat, v-mat).
    float4 pA0, pA1, pA2, pA3;
    {
        const float4* q = (const float4*)(key + ((size_t)gw << 10));
        pA0 = q[lane]; pA1 = q[lane + 64]; pA2 = q[lane + 128]; pA3 = q[lane + 192];
    }

    for (int l = 0; l < LNUM; ++l) {
        const float* cx = (l == 0) ? x_in : xbuf;
        const float* keyl = key + (size_t)l * 3 * EDIM * EDIM;
        const float* owl = ow + (size_t)l * EDIM * EDIM;
        const float* kfl = kffn + (size_t)l * FDIM * EDIM;
        const float* rfl = rffn + (size_t)l * EDIM * EDIM;
        const float* vfl = vffn + (size_t)l * EDIM * FDIM;
        const int le = l * EDIM;

        // ================= Phase A: LN1 + k/v/r matvecs =================
        {
            const float2 xv = cload2(cx + 2 * t);
            float s = xv.x + xv.y, s2 = xv.x * xv.x + xv.y * xv.y;
#pragma unroll
            for (int off = 32; off > 0; off >>= 1) {
                s += __shfl_xor(s, off, 64);
                s2 += __shfl_xor(s2, off, 64);
            }
            if (lane == 0) { red[w] = s; red[8 + w] = s2; }
            __syncthreads();
            float ts = 0.0f, ts2 = 0.0f;
#pragma unroll
            for (int i = 0; i < 8; ++i) { ts += red[i]; ts2 += red[8 + i]; }
            const float mu = ts * (1.0f / 1024.0f);
            const float inv = rsqrtf(ts2 * (1.0f / 1024.0f) - mu * mu + 1e-5f);
            const float2 wv = ((const float2*)(ln1w + le))[t];
            const float2 bv = ((const float2*)(ln1b + le))[t];
            const float2 xn = make_float2((xv.x - mu) * inv * wv.x + bv.x,
                                          (xv.y - mu) * inv * wv.y + bv.y);
            if (b == 0) ((float2*)(sa_out + le))[t] = xn;  // sa
            const float2 sav = ((const float2*)(state + le))[t];
            const float2 mk = ((const float2*)(mixk + le))[t];
            const float2 mv = ((const float2*)(mixv + le))[t];
            const float2 mr = ((const float2*)(mixr + le))[t];
            ((float2*)smem)[t] = make_float2(xn.x + mk.x * sav.x, xn.y + mk.y * sav.y);
            ((float2*)(smem + 1024))[t] = make_float2(xn.x + mv.x * sav.x, xn.y + mv.y * sav.y);
            ((float2*)(smem + 2048))[t] = make_float2(xn.x + mr.x * sav.x, xn.y + mr.y * sav.y);
            __syncthreads();
            const int mat = gw >> 10;  // 0 -> k row, 1 -> v row (prefetched)
            const float d1 = dot1024_pref(pA0, pA1, pA2, pA3, smem + (mat << 10), lane);
            if (lane == 0) {
                if (mat == 0) cstore1(kbuf + gw, expf(d1));
                else          cstore1(vbuf + gw - 1024, d1);
            }
            // balanced in-phase r-mat: row (b*4 + w/2), half (w&1) per wave
            const int rrow = (b << 2) + (w >> 1);
            const int rh = w & 1;
            const float d2 = dot512_mem(keyl + ((size_t)(2048 + rrow) << 10) + (rh << 9),
                                        smem + 2048 + (rh << 9), lane);
            if (lane == 0) red[16 + w] = d2;
            __syncthreads();
            if (t < 4)
                cstore1(rbuf + (b << 2) + t, expf(red[16 + 2 * t] + red[17 + 2 * t]) + 1.0f);
        }
        gbar_arrive(grp, gcnt, rel, bi);
        // -- window A->B: pB (ow half-row) + pC1 (kfw row gw) stream during poll
        float4 pB0, pB1, pC10, pC11, pC12, pC13;
        {
            const float4* qB = (const float4*)(owl + (((b << 2) + (w >> 1)) << 10) +
                                               ((w & 1) << 9));
            pB0 = qB[lane]; pB1 = qB[lane + 64];
            const float4* q1 = (const float4*)(kfl + ((size_t)gw << 10));
            pC10 = q1[lane]; pC11 = q1[lane + 64]; pC12 = q1[lane + 128]; pC13 = q1[lane + 192];
        }
        gbar_wait(rel, bi); ++bi;

        // ================= Phase B: WKV + ow matvec + residual =================
        {
            const float2 k2 = cload2(kbuf + 2 * t);
            const float2 v2 = cload2(vbuf + 2 * t);
            const float2 r2 = cload2(rbuf + 2 * t);
            const float2 tf2 = ((const float2*)(tf + le))[t];
            const float2 sb2 = ((const float2*)(state + 1 * LNUM * EDIM + le))[t];
            const float2 sc2 = ((const float2*)(state + 2 * LNUM * EDIM + le))[t];
            const float g0 = (sb2.x + tf2.x * k2.x * v2.x) / (sc2.x * r2.x + tf2.x * k2.x * r2.x);
            const float g1 = (sb2.y + tf2.y * k2.y * v2.y) / (sc2.y * r2.y + tf2.y * k2.y * r2.y);
            ((float2*)smem)[t] = make_float2(g0, g1);
            if (b == 0) {  // state outputs: host-visible at kernel end, normal stores
                const float2 td2 = ((const float2*)(td + le))[t];
                ((float2*)(sb_out + le))[t] =
                    make_float2(sb2.x * td2.x + k2.x * v2.x, sb2.y * td2.y + k2.y * v2.y);
                ((float2*)(sc_out + le))[t] =
                    make_float2(sc2.x * td2.x + k2.x, sc2.y * td2.y + k2.y);
            }
            __syncthreads();
            const float pd = dot512_pref(pB0, pB1, smem + ((w & 1) << 9), lane);
            if (lane == 0) red[w] = pd;
            __syncthreads();
            if (t < 4) {
                const int r = (b << 2) + t;
                cstore1(sxbuf + r, cload1(cx + r) + red[2 * t] + red[2 * t + 1]);
            }
        }
        gbar_arrive(grp, gcnt, rel, bi);
        // -- window B->C: pC2 (kfw row gw+2048)
        float4 pC20, pC21, pC22, pC23;
        {
            const float4* q2 = (const float4*)(kfl + ((size_t)(gw + 2048) << 10));
            pC20 = q2[lane]; pC21 = q2[lane + 64]; pC22 = q2[lane + 128]; pC23 = q2[lane + 192];
        }
        gbar_wait(rel, bi); ++bi;

        // ================= Phase C: LN2 + kfw/rfw matvecs =================
        {
            const float2 sxv = cload2(sxbuf + 2 * t);
            float s = sxv.x + sxv.y, s2 = sxv.x * sxv.x + sxv.y * sxv.y;
#pragma unroll
            for (int off = 32; off > 0; off >>= 1) {
                s += __shfl_xor(s, off, 64);
                s2 += __shfl_xor(s2, off, 64);
            }
            if (lane == 0) { red[w] = s; red[8 + w] = s2; }
            __syncthreads();
            float ts = 0.0f, ts2 = 0.0f;
#pragma unroll
            for (int i = 0; i < 8; ++i) { ts += red[i]; ts2 += red[8 + i]; }
            const float mu = ts * (1.0f / 1024.0f);
            const float inv = rsqrtf(ts2 * (1.0f / 1024.0f) - mu * mu + 1e-5f);
            const float2 wv = ((const float2*)(ln2w + le))[t];
            const float2 bv = ((const float2*)(ln2b + le))[t];
            const float2 x2 = make_float2((sxv.x - mu) * inv * wv.x + bv.x,
                                          (sxv.y - mu) * inv * wv.y + bv.y);
            if (b == 0) ((float2*)(sd_out + le))[t] = x2;  // sd
            const float2 sdv = ((const float2*)(state + 3 * LNUM * EDIM + le))[t];
            const float2 mkf = ((const float2*)(mixkf + le))[t];
            const float2 mrf = ((const float2*)(mixrf + le))[t];
            ((float2*)smem)[t] = make_float2(x2.x + mkf.x * sdv.x, x2.y + mkf.y * sdv.y);
            ((float2*)(smem + 1024))[t] = make_float2(x2.x + mrf.x * sdv.x, x2.y + mrf.y * sdv.y);
            __syncthreads();
            const float d1 = dot1024_pref(pC10, pC11, pC12, pC13, smem, lane);
            if (lane == 0) { const float rl = fmaxf(d1, 0.0f); cstore1(kfbuf + gw, rl * rl); }
            const float d2 = dot1024_pref(pC20, pC21, pC22, pC23, smem, lane);
            if (lane == 0) { const float rl = fmaxf(d2, 0.0f); cstore1(kfbuf + gw + 2048, rl * rl); }
            // balanced in-phase rfw: row (b*4 + w/2), half (w&1) per wave
            const int rrow = (b << 2) + (w >> 1);
            const int rh = w & 1;
            const float d3 = dot512_mem(rfl + ((size_t)rrow << 10) + (rh << 9),
                                        smem + 1024 + (rh << 9), lane);
            if (lane == 0) red[16 + w] = d3;
            __syncthreads();
            if (t < 4)
                cstore1(rdiv + (b << 2) + t,
                        1.0f / (1.0f + expf(red[16 + 2 * t] + red[17 + 2 * t])));
        }
        gbar_arrive(grp, gcnt, rel, bi);
        // -- window C->D: both vfw chunk-units
        const int drow = (b << 2) + (w >> 2);
        const int dch = w & 3;
        float4 pD0, pD1, pD2, pD3, pD4, pD5, pD6, pD7;
        {
            const float4* q1 = (const float4*)(vfl + ((size_t)drow << 12) + (dch << 10));
            pD0 = q1[lane]; pD1 = q1[lane + 64]; pD2 = q1[lane + 128]; pD3 = q1[lane + 192];
            const float4* q2 = (const float4*)(vfl + ((size_t)(drow + 2) << 12) + (dch << 10));
            pD4 = q2[lane]; pD5 = q2[lane + 64]; pD6 = q2[lane + 128]; pD7 = q2[lane + 192];
        }
        gbar_wait(rel, bi); ++bi;

        // ================= Phase D: vfw matvec + gated residual =================
        {
            const double* kfd = (const double*)kfbuf;
#pragma unroll
            for (int j = 0; j < 4; ++j)
                ((double*)smem)[t + j * 512] =
                    __hip_atomic_load(kfd + t + j * 512, __ATOMIC_RELAXED,
                                      __HIP_MEMORY_SCOPE_AGENT);
            __syncthreads();
            const float pd0 = dot1024_pref(pD0, pD1, pD2, pD3, smem + (dch << 10), lane);
            const float pd1 = dot1024_pref(pD4, pD5, pD6, pD7, smem + (dch << 10), lane);
            if (lane == 0) { red[w] = pd0; red[8 + w] = pd1; }
            __syncthreads();
            if (t < 4) {
                const int r = (b << 2) + t;
                const float dsum = red[4 * t] + red[4 * t + 1] + red[4 * t + 2] + red[4 * t + 3];
                const float val = cload1(sxbuf + r) + dsum * cload1(rdiv + r);
                if (l == LNUM - 1) out[r] = val;        // host-visible at kernel end
                else cstore1(xbuf + r, val);            // consumed by A' of all blocks
            }
        }
        if (l < LNUM - 1) {
            gbar_arrive(grp, gcnt, rel, bi);
            // -- window D->A': next layer's phase-A row
            const float4* qA = (const float4*)(key + (size_t)(l + 1) * 3 * EDIM * EDIM +
                                               ((size_t)gw << 10));
            pA0 = qA[lane]; pA1 = qA[lane + 64]; pA2 = qA[lane + 128]; pA3 = qA[lane + 192];
            gbar_wait(rel, bi); ++bi;
        }
    }
}

extern "C" void kernel_launch(void* const* d_in, const int* in_sizes, int n_in,
                              void* d_out, int out_size, void* d_ws, size_t ws_size,
                              hipStream_t stream) {
    const float* x_in = (const float*)d_in[0];
    const float* state = (const float*)d_in[1];
    const float* ln1w = (const float*)d_in[2];
    const float* ln1b = (const float*)d_in[3];
    const float* ln2w = (const float*)d_in[4];
    const float* ln2b = (const float*)d_in[5];
    const float* td = (const float*)d_in[6];
    const float* tf = (const float*)d_in[7];
    const float* key = (const float*)d_in[8];
    const float* ow = (const float*)d_in[9];
    const float* mixk = (const float*)d_in[10];
    const float* mixv = (const float*)d_in[11];
    const float* mixr = (const float*)d_in[12];
    const float* mixkf = (const float*)d_in[13];
    const float* mixrf = (const float*)d_in[14];
    const float* kffn = (const float*)d_in[15];
    const float* rffn = (const float*)d_in[16];
    const float* vffn = (const float*)d_in[17];

    float* out = (float*)d_out;
    float* ws = (float*)d_ws;

    // Barrier state at 48 KB: 8 padded group counters (64B), gcnt, rel.
    unsigned* bar = (unsigned*)((char*)d_ws + 48 * 1024);
    unsigned* grp = bar;          // grp[g<<4], g=0..7
    unsigned* gcnt = bar + 256;   // +1024 B
    unsigned* rel = bar + 272;    // +1088 B

    hipMemsetAsync(bar, 0, 2048, stream);  // deterministic per replay
    rwkv_persistent<<<NB, NT, 0, stream>>>(x_in, state, ln1w, ln1b, ln2w, ln2b, td, tf,
                                           key, ow, mixk, mixv, mixr, mixkf, mixrf,
                                           kffn, rffn, vffn, out, ws, grp, gcnt, rel);
}

// Round 8
// 604.858 us; speedup vs baseline: 4.2302x; 1.0006x over previous
//
#include <hip/hip_runtime.h>

#define EDIM 1024
#define LNUM 24
#define FDIM 4096
#define NB 256   // persistent blocks, 1 per CU
#define NT 512   // 8 waves per block

__device__ __forceinline__ float wave_sum(float v) {
#pragma unroll
    for (int off = 32; off > 0; off >>= 1) v += __shfl_xor(v, off, 64);
    return v;
}

// Coherent (MALL-visible) accessors for cross-block data. No fences anywhere.
__device__ __forceinline__ float2 cload2(const float* p) {
    double d = __hip_atomic_load((const double*)p, __ATOMIC_RELAXED,
                                 __HIP_MEMORY_SCOPE_AGENT);
    float2 r;
    __builtin_memcpy(&r, &d, 8);
    return r;
}
__device__ __forceinline__ float cload1(const float* p) {
    return __hip_atomic_load(p, __ATOMIC_RELAXED, __HIP_MEMORY_SCOPE_AGENT);
}
__device__ __forceinline__ void cstore1(float* p, float v) {
    __hip_atomic_store(p, v, __ATOMIC_RELAXED, __HIP_MEMORY_SCOPE_AGENT);
}

// Pin ordering: stores above, prefetch loads below (needed for counted vmcnt).
#define FENCE()                                  \
    do {                                         \
        asm volatile("" ::: "memory");           \
        __builtin_amdgcn_sched_barrier(0);       \
    } while (0)

// Intra-block barrier that does NOT drain vmcnt: LDS writes drained (lgkmcnt),
// global prefetch loads stay in flight. Memory clobbers on both sides keep
// LDS reads from hoisting above the barrier (rule #18).
__device__ __forceinline__ void lbar() {
    asm volatile("s_waitcnt lgkmcnt(0)" ::: "memory");
    __builtin_amdgcn_sched_barrier(0);
    __builtin_amdgcn_s_barrier();
    asm volatile("" ::: "memory");
    __builtin_amdgcn_sched_barrier(0);
}

// Device-wide barrier with counted vmcnt: P = prefetch loads issued (after all
// of this phase's stores) that may remain in flight across the barrier.
// In-order vmcnt retirement => "outstanding <= P" proves all stores drained.
// Two-level arrival tree (8 XCD-group lines -> gcnt); pollers watch gcnt.
template <int P>
__device__ __forceinline__ void gbar(unsigned* grp, unsigned* gcnt, unsigned& bi) {
    asm volatile("s_waitcnt vmcnt(%0) lgkmcnt(0)" ::"i"(P) : "memory");
    __builtin_amdgcn_sched_barrier(0);
    __builtin_amdgcn_s_barrier();  // all waves of block: stores drained
    if (threadIdx.x == 0) {
        unsigned o = __hip_atomic_fetch_add(&grp[(blockIdx.x & 7) << 4], 1u,
                                            __ATOMIC_RELAXED, __HIP_MEMORY_SCOPE_AGENT);
        if ((o & 31u) == 31u)  // last of 32 blocks in this group
            __hip_atomic_fetch_add(gcnt, 1u, __ATOMIC_RELAXED,
                                   __HIP_MEMORY_SCOPE_AGENT);
        const unsigned tgt = 8u * (bi + 1u);
        int guard = 0;
        while (__hip_atomic_load(gcnt, __ATOMIC_RELAXED, __HIP_MEMORY_SCOPE_AGENT) <
               tgt) {
            __builtin_amdgcn_s_sleep(1);
            if (++guard > (1 << 20)) break;  // fail-fast bailout (~20ms)
        }
    }
    __builtin_amdgcn_s_barrier();
    asm volatile("" ::: "memory");
    __builtin_amdgcn_sched_barrier(0);
    ++bi;
}

__device__ __forceinline__ float dot16(const float4& p0, const float4& p1,
                                       const float4& p2, const float4& p3,
                                       const float4& a, const float4& b,
                                       const float4& c, const float4& d) {
    return p0.x * a.x + p0.y * a.y + p0.z * a.z + p0.w * a.w +
           p1.x * b.x + p1.y * b.y + p1.z * b.z + p1.w * b.w +
           p2.x * c.x + p2.y * c.y + p2.z * c.z + p2.w * c.w +
           p3.x * d.x + p3.y * d.y + p3.z * d.z + p3.w * d.w;
}

__device__ __forceinline__ float dot1024_pref(const float4& p0, const float4& p1,
                                              const float4& p2, const float4& p3,
                                              const float* op, int lane) {
    const float4* o = (const float4*)op;
    return wave_sum(dot16(p0, p1, p2, p3, o[lane], o[lane + 64], o[lane + 128],
                          o[lane + 192]));
}

__device__ __forceinline__ float dot512_pref(const float4& p0, const float4& p1,
                                             const float* op, int lane) {
    const float4* o = (const float4*)op;
    const float4 a = o[lane], b4 = o[lane + 64];
    return wave_sum(p0.x * a.x + p0.y * a.y + p0.z * a.z + p0.w * a.w +
                    p1.x * b4.x + p1.y * b4.y + p1.z * b4.z + p1.w * b4.w);
}

__global__ __launch_bounds__(NT, 2) void rwkv_persistent(
    const float* __restrict__ x_in, const float* __restrict__ state,
    const float* __restrict__ ln1w, const float* __restrict__ ln1b,
    const float* __restrict__ ln2w, const float* __restrict__ ln2b,
    const float* __restrict__ td, const float* __restrict__ tf,
    const float* __restrict__ key, const float* __restrict__ ow,
    const float* __restrict__ mixk, const float* __restrict__ mixv,
    const float* __restrict__ mixr, const float* __restrict__ mixkf,
    const float* __restrict__ mixrf, const float* __restrict__ kffn,
    const float* __restrict__ rffn, const float* __restrict__ vffn,
    float* __restrict__ out, float* __restrict__ ws, unsigned* __restrict__ grp,
    unsigned* __restrict__ gcnt) {
    __shared__ float smem[FDIM + 32];
    float* red = smem + FDIM;  // [0..7]=s, [8..15]=s2/pd1, [16..23]=half partials

    float* xbuf = ws;           // [1024] residual stream        (coherent)
    float* sxbuf = ws + 1024;   // [1024]
    float* kbuf = ws + 2048;    // [1024]
    float* vbuf = ws + 3072;    // [1024]
    float* rbuf = ws + 4096;    // [1024]
    float* kfbuf = ws + 5120;   // [4096]
    float* rdiv = ws + 9216;    // [1024]

    float* sa_out = out + EDIM;
    float* sb_out = sa_out + LNUM * EDIM;
    float* sc_out = sb_out + LNUM * EDIM;
    float* sd_out = sc_out + LNUM * EDIM;

    const int t = threadIdx.x;
    const int b = blockIdx.x;
    const int w = t >> 6;
    const int lane = t & 63;
    const int gw = (b << 3) + w;        // 0..2047
    const int rrow = (b << 2) + (w >> 1);  // shared by r-mat / ow / rfw halves
    const int rh = w & 1;
    const int drow = (b << 2) + (w >> 2);
    const int dch = w & 3;
    unsigned bi = 0;

    // Prefetch registers (named, never runtime-indexed — rule #20)
    float4 pA0, pA1, pA2, pA3, rA0, rA1;
    float4 pB0, pB1;
    float4 pC10, pC11, pC12, pC13, pC20, pC21, pC22, pC23, rC0, rC1;
    float4 pD0, pD1, pD2, pD3, pD4, pD5, pD6, pD7;

    // Prologue: layer-0 phase-A weights (k/v full row gw; r half-row).
    {
        const float4* qA = (const float4*)(key + ((size_t)gw << 10));
        pA0 = qA[lane]; pA1 = qA[lane + 64]; pA2 = qA[lane + 128]; pA3 = qA[lane + 192];
        const float4* qR =
            (const float4*)(key + ((size_t)(2048 + rrow) << 10) + (rh << 9));
        rA0 = qR[lane]; rA1 = qR[lane + 64];
    }

    for (int l = 0; l < LNUM; ++l) {
        const float* cx = (l == 0) ? x_in : xbuf;
        const float* owl = ow + (size_t)l * EDIM * EDIM;
        const float* kfl = kffn + (size_t)l * FDIM * EDIM;
        const float* rfl = rffn + (size_t)l * EDIM * EDIM;
        const float* vfl = vffn + (size_t)l * EDIM * FDIM;
        const int le = l * EDIM;

        // ================= Phase A: LN1 + k/v/r matvecs =================
        {
            const float2 xv = cload2(cx + 2 * t);
            float s = xv.x + xv.y, s2 = xv.x * xv.x + xv.y * xv.y;
#pragma unroll
            for (int off = 32; off > 0; off >>= 1) {
                s += __shfl_xor(s, off, 64);
                s2 += __shfl_xor(s2, off, 64);
            }
            if (lane == 0) { red[w] = s; red[8 + w] = s2; }
            lbar();
            float ts = 0.0f, ts2 = 0.0f;
#pragma unroll
            for (int i = 0; i < 8; ++i) { ts += red[i]; ts2 += red[8 + i]; }
            const float mu = ts * (1.0f / 1024.0f);
            const float inv = rsqrtf(ts2 * (1.0f / 1024.0f) - mu * mu + 1e-5f);
            const float2 wv = ((const float2*)(ln1w + le))[t];
            const float2 bv = ((const float2*)(ln1b + le))[t];
            const float2 xn = make_float2((xv.x - mu) * inv * wv.x + bv.x,
                                          (xv.y - mu) * inv * wv.y + bv.y);
            if (b == 0) ((float2*)(sa_out + le))[t] = xn;  // sa
            const float2 sav = ((const float2*)(state + le))[t];
            const float2 mk = ((const float2*)(mixk + le))[t];
            const float2 mv = ((const float2*)(mixv + le))[t];
            const float2 mr = ((const float2*)(mixr + le))[t];
            ((float2*)smem)[t] = make_float2(xn.x + mk.x * sav.x, xn.y + mk.y * sav.y);
            ((float2*)(smem + 1024))[t] =
                make_float2(xn.x + mv.x * sav.x, xn.y + mv.y * sav.y);
            ((float2*)(smem + 2048))[t] =
                make_float2(xn.x + mr.x * sav.x, xn.y + mr.y * sav.y);
            lbar();
            const int mat = gw >> 10;  // 0 -> k row, 1 -> v row (prefetched)
            const float d1 = dot1024_pref(pA0, pA1, pA2, pA3, smem + (mat << 10), lane);
            if (lane == 0) {
                if (mat == 0) cstore1(kbuf + gw, expf(d1));
                else          cstore1(vbuf + gw - 1024, d1);
            }
            const float d2 = dot512_pref(rA0, rA1, smem + 2048 + (rh << 9), lane);
            if (lane == 0) red[16 + w] = d2;
            lbar();
            if (t < 4)
                cstore1(rbuf + (b << 2) + t,
                        expf(red[16 + 2 * t] + red[17 + 2 * t]) + 1.0f);
        }
        FENCE();
        {   // issue B + C weights (12 loads/lane, stay in flight across barrier)
            const float4* qB = (const float4*)(owl + ((size_t)rrow << 10) + (rh << 9));
            pB0 = qB[lane]; pB1 = qB[lane + 64];
            const float4* q1 = (const float4*)(kfl + ((size_t)gw << 10));
            pC10 = q1[lane]; pC11 = q1[lane + 64]; pC12 = q1[lane + 128]; pC13 = q1[lane + 192];
            const float4* q2 = (const float4*)(kfl + ((size_t)(gw + 2048) << 10));
            pC20 = q2[lane]; pC21 = q2[lane + 64]; pC22 = q2[lane + 128]; pC23 = q2[lane + 192];
            const float4* qR = (const float4*)(rfl + ((size_t)rrow << 10) + (rh << 9));
            rC0 = qR[lane]; rC1 = qR[lane + 64];
        }
        gbar<12>(grp, gcnt, bi);

        // ================= Phase B: WKV + ow matvec + residual =================
        {
            const float2 k2 = cload2(kbuf + 2 * t);
            const float2 v2 = cload2(vbuf + 2 * t);
            const float2 r2 = cload2(rbuf + 2 * t);
            const float2 tf2 = ((const float2*)(tf + le))[t];
            const float2 sb2 = ((const float2*)(state + 1 * LNUM * EDIM + le))[t];
            const float2 sc2 = ((const float2*)(state + 2 * LNUM * EDIM + le))[t];
            const float g0 =
                (sb2.x + tf2.x * k2.x * v2.x) / (sc2.x * r2.x + tf2.x * k2.x * r2.x);
            const float g1 =
                (sb2.y + tf2.y * k2.y * v2.y) / (sc2.y * r2.y + tf2.y * k2.y * r2.y);
            ((float2*)smem)[t] = make_float2(g0, g1);
            if (b == 0) {
                const float2 td2 = ((const float2*)(td + le))[t];
                ((float2*)(sb_out + le))[t] =
                    make_float2(sb2.x * td2.x + k2.x * v2.x, sb2.y * td2.y + k2.y * v2.y);
                ((float2*)(sc_out + le))[t] =
                    make_float2(sc2.x * td2.x + k2.x, sc2.y * td2.y + k2.y);
            }
            lbar();
            const float pd = dot512_pref(pB0, pB1, smem + (rh << 9), lane);
            if (lane == 0) red[w] = pd;
            lbar();
            if (t < 4) {
                const int r = (b << 2) + t;
                cstore1(sxbuf + r, cload1(cx + r) + red[2 * t] + red[2 * t + 1]);
            }
        }
        FENCE();
        {   // issue D weights (8 loads/lane)
            const float4* q1 = (const float4*)(vfl + ((size_t)drow << 12) + (dch << 10));
            pD0 = q1[lane]; pD1 = q1[lane + 64]; pD2 = q1[lane + 128]; pD3 = q1[lane + 192];
            const float4* q2 =
                (const float4*)(vfl + ((size_t)(drow + 2) << 12) + (dch << 10));
            pD4 = q2[lane]; pD5 = q2[lane + 64]; pD6 = q2[lane + 128]; pD7 = q2[lane + 192];
        }
        gbar<8>(grp, gcnt, bi);

        // ================= Phase C: LN2 + kfw/rfw matvecs =================
        {
            const float2 sxv = cload2(sxbuf + 2 * t);
            float s = sxv.x + sxv.y, s2 = sxv.x * sxv.x + sxv.y * sxv.y;
#pragma unroll
            for (int off = 32; off > 0; off >>= 1) {
                s += __shfl_xor(s, off, 64);
                s2 += __shfl_xor(s2, off, 64);
            }
            if (lane == 0) { red[w] = s; red[8 + w] = s2; }
            lbar();
            float ts = 0.0f, ts2 = 0.0f;
#pragma unroll
            for (int i = 0; i < 8; ++i) { ts += red[i]; ts2 += red[8 + i]; }
            const float mu = ts * (1.0f / 1024.0f);
            const float inv = rsqrtf(ts2 * (1.0f / 1024.0f) - mu * mu + 1e-5f);
            const float2 wv = ((const float2*)(ln2w + le))[t];
            const float2 bv = ((const float2*)(ln2b + le))[t];
            const float2 x2 = make_float2((sxv.x - mu) * inv * wv.x + bv.x,
                                          (sxv.y - mu) * inv * wv.y + bv.y);
            if (b == 0) ((float2*)(sd_out + le))[t] = x2;  // sd
            const float2 sdv = ((const float2*)(state + 3 * LNUM * EDIM + le))[t];
            const float2 mkf = ((const float2*)(mixkf + le))[t];
            const float2 mrf = ((const float2*)(mixrf + le))[t];
            ((float2*)smem)[t] = make_float2(x2.x + mkf.x * sdv.x, x2.y + mkf.y * sdv.y);
            ((float2*)(smem + 1024))[t] =
                make_float2(x2.x + mrf.x * sdv.x, x2.y + mrf.y * sdv.y);
            lbar();
            const float d1 = dot1024_pref(pC10, pC11, pC12, pC13, smem, lane);
            if (lane == 0) { const float rl = fmaxf(d1, 0.0f); cstore1(kfbuf + gw, rl * rl); }
            const float d2 = dot1024_pref(pC20, pC21, pC22, pC23, smem, lane);
            if (lane == 0) { const float rl = fmaxf(d2, 0.0f); cstore1(kfbuf + gw + 2048, rl * rl); }
            const float d3 = dot512_pref(rC0, rC1, smem + 1024 + (rh << 9), lane);
            if (lane == 0) red[16 + w] = d3;
            lbar();
            if (t < 4)
                cstore1(rdiv + (b << 2) + t,
                        1.0f / (1.0f + expf(red[16 + 2 * t] + red[17 + 2 * t])));
        }
        gbar<0>(grp, gcnt, bi);  // pD (issued at B end) has streamed through C

        // ================= Phase D: vfw matvec + gated residual =================
        {
            const double* kfd = (const double*)kfbuf;
#pragma unroll
            for (int j = 0; j < 4; ++j)
                ((double*)smem)[t + j * 512] = __hip_atomic_load(
                    kfd + t + j * 512, __ATOMIC_RELAXED, __HIP_MEMORY_SCOPE_AGENT);
            lbar();
            const float pd0 = dot1024_pref(pD0, pD1, pD2, pD3, smem + (dch << 10), lane);
            const float pd1 = dot1024_pref(pD4, pD5, pD6, pD7, smem + (dch << 10), lane);
            if (lane == 0) { red[w] = pd0; red[8 + w] = pd1; }
            lbar();
            if (t < 4) {
                const int r = (b << 2) + t;
                const float dsum =
                    red[4 * t] + red[4 * t + 1] + red[4 * t + 2] + red[4 * t + 3];
                const float val = cload1(sxbuf + r) + dsum * cload1(rdiv + r);
                if (l == LNUM - 1) out[r] = val;  // host-visible at kernel end
                else cstore1(xbuf + r, val);
            }
        }
        if (l < LNUM - 1) {
            FENCE();
            {   // issue next layer's phase-A weights (6 loads/lane)
                const float* keyn = key + (size_t)(l + 1) * 3 * EDIM * EDIM;
                const float4* qA = (const float4*)(keyn + ((size_t)gw << 10));
                pA0 = qA[lane]; pA1 = qA[lane + 64]; pA2 = qA[lane + 128]; pA3 = qA[lane + 192];
                const float4* qR =
                    (const float4*)(keyn + ((size_t)(2048 + rrow) << 10) + (rh << 9));
                rA0 = qR[lane]; rA1 = qR[lane + 64];
            }
            gbar<6>(grp, gcnt, bi);
        }
    }
}

extern "C" void kernel_launch(void* const* d_in, const int* in_sizes, int n_in,
                              void* d_out, int out_size, void* d_ws, size_t ws_size,
                              hipStream_t stream) {
    const float* x_in = (const float*)d_in[0];
    const float* state = (const float*)d_in[1];
    const float* ln1w = (const float*)d_in[2];
    const float* ln1b = (const float*)d_in[3];
    const float* ln2w = (const float*)d_in[4];
    const float* ln2b = (const float*)d_in[5];
    const float* td = (const float*)d_in[6];
    const float* tf = (const float*)d_in[7];
    const float* key = (const float*)d_in[8];
    const float* ow = (const float*)d_in[9];
    const float* mixk = (const float*)d_in[10];
    const float* mixv = (const float*)d_in[11];
    const float* mixr = (const float*)d_in[12];
    const float* mixkf = (const float*)d_in[13];
    const float* mixrf = (const float*)d_in[14];
    const float* kffn = (const float*)d_in[15];
    const float* rffn = (const float*)d_in[16];
    const float* vffn = (const float*)d_in[17];

    float* out = (float*)d_out;
    float* ws = (float*)d_ws;

    // Barrier state at 48 KB: 8 padded group counters (64B lines) + gcnt.
    unsigned* bar = (unsigned*)((char*)d_ws + 48 * 1024);
    unsigned* grp = bar;         // grp[g<<4], g=0..7
    unsigned* gcnt = bar + 256;  // separate line

    hipMemsetAsync(bar, 0, 2048, stream);  // deterministic per replay
    rwkv_persistent<<<NB, NT, 0, stream>>>(x_in, state, ln1w, ln1b, ln2w, ln2b, td, tf,
                                           key, ow, mixk, mixv, mixr, mixkf, mixrf,
                                           kffn, rffn, vffn, out, ws, grp, gcnt);
}

// Round 9
// 537.540 us; speedup vs baseline: 4.7600x; 1.1252x over previous
//
#include <hip/hip_runtime.h>

#define EDIM 1024
#define LNUM 24
#define FDIM 4096
#define NB 256   // persistent blocks, 1 per CU
#define NT 512   // 8 waves per block

__device__ __forceinline__ float wave_sum(float v) {
#pragma unroll
    for (int off = 32; off > 0; off >>= 1) v += __shfl_xor(v, off, 64);
    return v;
}

// Coherent (MALL-visible) accessors for cross-block data. No fences anywhere.
__device__ __forceinline__ float2 cload2(const float* p) {
    double d = __hip_atomic_load((const double*)p, __ATOMIC_RELAXED,
                                 __HIP_MEMORY_SCOPE_AGENT);
    float2 r;
    __builtin_memcpy(&r, &d, 8);
    return r;
}
__device__ __forceinline__ float cload1(const float* p) {
    return __hip_atomic_load(p, __ATOMIC_RELAXED, __HIP_MEMORY_SCOPE_AGENT);
}
__device__ __forceinline__ void cstore1(float* p, float v) {
    __hip_atomic_store(p, v, __ATOMIC_RELAXED, __HIP_MEMORY_SCOPE_AGENT);
}

// Pin ordering: stores above, prefetch loads below (needed for counted vmcnt).
#define FENCE()                                  \
    do {                                         \
        asm volatile("" ::: "memory");           \
        __builtin_amdgcn_sched_barrier(0);       \
    } while (0)

// Intra-block barrier that does NOT drain vmcnt.
__device__ __forceinline__ void lbar() {
    asm volatile("s_waitcnt lgkmcnt(0)" ::: "memory");
    __builtin_amdgcn_sched_barrier(0);
    __builtin_amdgcn_s_barrier();
    asm volatile("" ::: "memory");
    __builtin_amdgcn_sched_barrier(0);
}

// Device-wide barrier, counted vmcnt (P = prefetch loads allowed in flight).
// Arrival: 8 group lines x 32 atomics. Release tree: each group-last polls the
// 8 group counters (8 pollers only), then writes 32 per-block flag lines; every
// other block polls its OWN flag line (1 poller per line -> no MALL same-line
// contention, which was the round-7/8 ~4us/barrier cost).
template <int P>
__device__ __forceinline__ void gbar(unsigned* grp, unsigned* flags, unsigned& bi) {
    asm volatile("s_waitcnt vmcnt(%0) lgkmcnt(0)" ::"i"(P) : "memory");
    __builtin_amdgcn_sched_barrier(0);
    __builtin_amdgcn_s_barrier();  // all waves of block: stores drained
    const unsigned bi1 = bi + 1u;
    if (threadIdx.x == 0) {
        const int g = blockIdx.x & 7;
        unsigned o = __hip_atomic_fetch_add(&grp[g << 4], 1u, __ATOMIC_RELAXED,
                                            __HIP_MEMORY_SCOPE_AGENT);
        if ((o & 31u) == 31u) {  // group-last for this epoch
            const unsigned tgt = 32u * bi1;
            int guard = 0;
            for (;;) {
                unsigned mn = 0xffffffffu;
#pragma unroll
                for (int i = 0; i < 8; ++i) {
                    unsigned v = __hip_atomic_load(&grp[i << 4], __ATOMIC_RELAXED,
                                                   __HIP_MEMORY_SCOPE_AGENT);
                    mn = (v < mn) ? v : mn;
                }
                if (mn >= tgt) break;
                __builtin_amdgcn_s_sleep(1);
                if (++guard > (1 << 20)) break;  // fail-fast bailout
            }
            // release this group's 32 blocks (one private flag line each)
#pragma unroll 4
            for (int j = 0; j < 32; ++j)
                __hip_atomic_store(&flags[(g + 8 * j) << 4], bi1, __ATOMIC_RELAXED,
                                   __HIP_MEMORY_SCOPE_AGENT);
        } else {
            int guard = 0;
            while (__hip_atomic_load(&flags[blockIdx.x << 4], __ATOMIC_RELAXED,
                                     __HIP_MEMORY_SCOPE_AGENT) < bi1) {
                __builtin_amdgcn_s_sleep(1);
                if (++guard > (1 << 20)) break;
            }
        }
    }
    __builtin_amdgcn_s_barrier();
    asm volatile("" ::: "memory");
    __builtin_amdgcn_sched_barrier(0);
    ++bi;
}

__device__ __forceinline__ float dot16(const float4& p0, const float4& p1,
                                       const float4& p2, const float4& p3,
                                       const float4& a, const float4& b,
                                       const float4& c, const float4& d) {
    return p0.x * a.x + p0.y * a.y + p0.z * a.z + p0.w * a.w +
           p1.x * b.x + p1.y * b.y + p1.z * b.z + p1.w * b.w +
           p2.x * c.x + p2.y * c.y + p2.z * c.z + p2.w * c.w +
           p3.x * d.x + p3.y * d.y + p3.z * d.z + p3.w * d.w;
}

__device__ __forceinline__ float dot1024_pref(const float4& p0, const float4& p1,
                                              const float4& p2, const float4& p3,
                                              const float* op, int lane) {
    const float4* o = (const float4*)op;
    return wave_sum(dot16(p0, p1, p2, p3, o[lane], o[lane + 64], o[lane + 128],
                          o[lane + 192]));
}

__device__ __forceinline__ float dot512_pref(const float4& p0, const float4& p1,
                                             const float* op, int lane) {
    const float4* o = (const float4*)op;
    const float4 a = o[lane], b4 = o[lane + 64];
    return wave_sum(p0.x * a.x + p0.y * a.y + p0.z * a.z + p0.w * a.w +
                    p1.x * b4.x + p1.y * b4.y + p1.z * b4.z + p1.w * b4.w);
}

__global__ __launch_bounds__(NT, 2) void rwkv_persistent(
    const float* __restrict__ x_in, const float* __restrict__ state,
    const float* __restrict__ ln1w, const float* __restrict__ ln1b,
    const float* __restrict__ ln2w, const float* __restrict__ ln2b,
    const float* __restrict__ td, const float* __restrict__ tf,
    const float* __restrict__ key, const float* __restrict__ ow,
    const float* __restrict__ mixk, const float* __restrict__ mixv,
    const float* __restrict__ mixr, const float* __restrict__ mixkf,
    const float* __restrict__ mixrf, const float* __restrict__ kffn,
    const float* __restrict__ rffn, const float* __restrict__ vffn,
    float* __restrict__ out, float* __restrict__ ws, unsigned* __restrict__ grp,
    unsigned* __restrict__ flags) {
    __shared__ float smem[FDIM + 32];
    float* red = smem + FDIM;  // [0..7]=s, [8..15]=s2/pd1, [16..23]=half partials

    float* xbuf = ws;           // [1024] residual stream        (coherent)
    float* sxbuf = ws + 1024;   // [1024]
    float* kbuf = ws + 2048;    // [1024]
    float* vbuf = ws + 3072;    // [1024]
    float* rbuf = ws + 4096;    // [1024]
    float* kfbuf = ws + 5120;   // [4096]
    float* rdiv = ws + 9216;    // [1024]

    float* sa_out = out + EDIM;
    float* sb_out = sa_out + LNUM * EDIM;
    float* sc_out = sb_out + LNUM * EDIM;
    float* sd_out = sc_out + LNUM * EDIM;

    const int t = threadIdx.x;
    const int b = blockIdx.x;
    const int w = t >> 6;
    const int lane = t & 63;
    const int gw = (b << 3) + w;           // 0..2047
    const int rrow = (b << 2) + (w >> 1);  // shared by r-mat / ow / rfw halves
    const int rh = w & 1;
    const int drow = (b << 2) + (w >> 2);
    const int dch = w & 3;
    unsigned bi = 0;

    // Prefetch registers (named, never runtime-indexed — rule #20)
    float4 pA0, pA1, pA2, pA3, rA0, rA1;
    float4 pB0, pB1;
    float4 pC10, pC11, pC12, pC13, pC20, pC21, pC22, pC23, rC0, rC1;
    float4 pD0, pD1, pD2, pD3, pD4, pD5, pD6, pD7;

    // Prologue: layer-0 phase-A weights (k/v full row gw; r half-row).
    {
        const float4* qA = (const float4*)(key + ((size_t)gw << 10));
        pA0 = qA[lane]; pA1 = qA[lane + 64]; pA2 = qA[lane + 128]; pA3 = qA[lane + 192];
        const float4* qR =
            (const float4*)(key + ((size_t)(2048 + rrow) << 10) + (rh << 9));
        rA0 = qR[lane]; rA1 = qR[lane + 64];
    }

    for (int l = 0; l < LNUM; ++l) {
        const float* cx = (l == 0) ? x_in : xbuf;
        const float* owl = ow + (size_t)l * EDIM * EDIM;
        const float* kfl = kffn + (size_t)l * FDIM * EDIM;
        const float* rfl = rffn + (size_t)l * EDIM * EDIM;
        const float* vfl = vffn + (size_t)l * EDIM * FDIM;
        const int le = l * EDIM;

        // ================= Phase A: LN1 + k/v/r matvecs =================
        {
            const float2 xv = cload2(cx + 2 * t);
            float s = xv.x + xv.y, s2 = xv.x * xv.x + xv.y * xv.y;
#pragma unroll
            for (int off = 32; off > 0; off >>= 1) {
                s += __shfl_xor(s, off, 64);
                s2 += __shfl_xor(s2, off, 64);
            }
            if (lane == 0) { red[w] = s; red[8 + w] = s2; }
            lbar();
            float ts = 0.0f, ts2 = 0.0f;
#pragma unroll
            for (int i = 0; i < 8; ++i) { ts += red[i]; ts2 += red[8 + i]; }
            const float mu = ts * (1.0f / 1024.0f);
            const float inv = rsqrtf(ts2 * (1.0f / 1024.0f) - mu * mu + 1e-5f);
            const float2 wv = ((const float2*)(ln1w + le))[t];
            const float2 bv = ((const float2*)(ln1b + le))[t];
            const float2 xn = make_float2((xv.x - mu) * inv * wv.x + bv.x,
                                          (xv.y - mu) * inv * wv.y + bv.y);
            if (b == 0) ((float2*)(sa_out + le))[t] = xn;  // sa
            const float2 sav = ((const float2*)(state + le))[t];
            const float2 mk = ((const float2*)(mixk + le))[t];
            const float2 mv = ((const float2*)(mixv + le))[t];
            const float2 mr = ((const float2*)(mixr + le))[t];
            ((float2*)smem)[t] = make_float2(xn.x + mk.x * sav.x, xn.y + mk.y * sav.y);
            ((float2*)(smem + 1024))[t] =
                make_float2(xn.x + mv.x * sav.x, xn.y + mv.y * sav.y);
            ((float2*)(smem + 2048))[t] =
                make_float2(xn.x + mr.x * sav.x, xn.y + mr.y * sav.y);
            lbar();
            const int mat = gw >> 10;  // 0 -> k row, 1 -> v row (prefetched)
            const float d1 = dot1024_pref(pA0, pA1, pA2, pA3, smem + (mat << 10), lane);
            if (lane == 0) {
                if (mat == 0) cstore1(kbuf + gw, expf(d1));
                else          cstore1(vbuf + gw - 1024, d1);
            }
            const float d2 = dot512_pref(rA0, rA1, smem + 2048 + (rh << 9), lane);
            if (lane == 0) red[16 + w] = d2;
            lbar();
            if (t < 4)
                cstore1(rbuf + (b << 2) + t,
                        expf(red[16 + 2 * t] + red[17 + 2 * t]) + 1.0f);
        }
        FENCE();
        {   // issue B + C weights (12 loads/lane, stay in flight across barrier)
            const float4* qB = (const float4*)(owl + ((size_t)rrow << 10) + (rh << 9));
            pB0 = qB[lane]; pB1 = qB[lane + 64];
            const float4* q1 = (const float4*)(kfl + ((size_t)gw << 10));
            pC10 = q1[lane]; pC11 = q1[lane + 64]; pC12 = q1[lane + 128]; pC13 = q1[lane + 192];
            const float4* q2 = (const float4*)(kfl + ((size_t)(gw + 2048) << 10));
            pC20 = q2[lane]; pC21 = q2[lane + 64]; pC22 = q2[lane + 128]; pC23 = q2[lane + 192];
            const float4* qR = (const float4*)(rfl + ((size_t)rrow << 10) + (rh << 9));
            rC0 = qR[lane]; rC1 = qR[lane + 64];
        }
        gbar<12>(grp, flags, bi);

        // ================= Phase B: WKV + ow matvec + residual =================
        {
            const float2 k2 = cload2(kbuf + 2 * t);
            const float2 v2 = cload2(vbuf + 2 * t);
            const float2 r2 = cload2(rbuf + 2 * t);
            const float2 tf2 = ((const float2*)(tf + le))[t];
            const float2 sb2 = ((const float2*)(state + 1 * LNUM * EDIM + le))[t];
            const float2 sc2 = ((const float2*)(state + 2 * LNUM * EDIM + le))[t];
            const float g0 =
                (sb2.x + tf2.x * k2.x * v2.x) / (sc2.x * r2.x + tf2.x * k2.x * r2.x);
            const float g1 =
                (sb2.y + tf2.y * k2.y * v2.y) / (sc2.y * r2.y + tf2.y * k2.y * r2.y);
            ((float2*)smem)[t] = make_float2(g0, g1);
            if (b == 0) {
                const float2 td2 = ((const float2*)(td + le))[t];
                ((float2*)(sb_out + le))[t] =
                    make_float2(sb2.x * td2.x + k2.x * v2.x, sb2.y * td2.y + k2.y * v2.y);
                ((float2*)(sc_out + le))[t] =
                    make_float2(sc2.x * td2.x + k2.x, sc2.y * td2.y + k2.y);
            }
            lbar();
            const float pd = dot512_pref(pB0, pB1, smem + (rh << 9), lane);
            if (lane == 0) red[w] = pd;
            lbar();
            if (t < 4) {
                const int r = (b << 2) + t;
                cstore1(sxbuf + r, cload1(cx + r) + red[2 * t] + red[2 * t + 1]);
            }
        }
        FENCE();
        {   // issue D weights (8 loads/lane)
            const float4* q1 = (const float4*)(vfl + ((size_t)drow << 12) + (dch << 10));
            pD0 = q1[lane]; pD1 = q1[lane + 64]; pD2 = q1[lane + 128]; pD3 = q1[lane + 192];
            const float4* q2 =
                (const float4*)(vfl + ((size_t)(drow + 2) << 12) + (dch << 10));
            pD4 = q2[lane]; pD5 = q2[lane + 64]; pD6 = q2[lane + 128]; pD7 = q2[lane + 192];
        }
        gbar<8>(grp, flags, bi);

        // ================= Phase C: LN2 + kfw/rfw matvecs =================
        {
            const float2 sxv = cload2(sxbuf + 2 * t);
            float s = sxv.x + sxv.y, s2 = sxv.x * sxv.x + sxv.y * sxv.y;
#pragma unroll
            for (int off = 32; off > 0; off >>= 1) {
                s += __shfl_xor(s, off, 64);
                s2 += __shfl_xor(s2, off, 64);
            }
            if (lane == 0) { red[w] = s; red[8 + w] = s2; }
            lbar();
            float ts = 0.0f, ts2 = 0.0f;
#pragma unroll
            for (int i = 0; i < 8; ++i) { ts += red[i]; ts2 += red[8 + i]; }
            const float mu = ts * (1.0f / 1024.0f);
            const float inv = rsqrtf(ts2 * (1.0f / 1024.0f) - mu * mu + 1e-5f);
            const float2 wv = ((const float2*)(ln2w + le))[t];
            const float2 bv = ((const float2*)(ln2b + le))[t];
            const float2 x2 = make_float2((sxv.x - mu) * inv * wv.x + bv.x,
                                          (sxv.y - mu) * inv * wv.y + bv.y);
            if (b == 0) ((float2*)(sd_out + le))[t] = x2;  // sd
            const float2 sdv = ((const float2*)(state + 3 * LNUM * EDIM + le))[t];
            const float2 mkf = ((const float2*)(mixkf + le))[t];
            const float2 mrf = ((const float2*)(mixrf + le))[t];
            ((float2*)smem)[t] = make_float2(x2.x + mkf.x * sdv.x, x2.y + mkf.y * sdv.y);
            ((float2*)(smem + 1024))[t] =
                make_float2(x2.x + mrf.x * sdv.x, x2.y + mrf.y * sdv.y);
            lbar();
            const float d1 = dot1024_pref(pC10, pC11, pC12, pC13, smem, lane);
            if (lane == 0) { const float rl = fmaxf(d1, 0.0f); cstore1(kfbuf + gw, rl * rl); }
            const float d2 = dot1024_pref(pC20, pC21, pC22, pC23, smem, lane);
            if (lane == 0) { const float rl = fmaxf(d2, 0.0f); cstore1(kfbuf + gw + 2048, rl * rl); }
            const float d3 = dot512_pref(rC0, rC1, smem + 1024 + (rh << 9), lane);
            if (lane == 0) red[16 + w] = d3;
            lbar();
            if (t < 4)
                cstore1(rdiv + (b << 2) + t,
                        1.0f / (1.0f + expf(red[16 + 2 * t] + red[17 + 2 * t])));
        }
        gbar<0>(grp, flags, bi);  // pD (issued at B end) has streamed through C

        // ================= Phase D: vfw matvec + gated residual =================
        {
            const double* kfd = (const double*)kfbuf;
#pragma unroll
            for (int j = 0; j < 4; ++j)
                ((double*)smem)[t + j * 512] = __hip_atomic_load(
                    kfd + t + j * 512, __ATOMIC_RELAXED, __HIP_MEMORY_SCOPE_AGENT);
            lbar();
            const float pd0 = dot1024_pref(pD0, pD1, pD2, pD3, smem + (dch << 10), lane);
            const float pd1 = dot1024_pref(pD4, pD5, pD6, pD7, smem + (dch << 10), lane);
            if (lane == 0) { red[w] = pd0; red[8 + w] = pd1; }
            lbar();
            if (t < 4) {
                const int r = (b << 2) + t;
                const float dsum =
                    red[4 * t] + red[4 * t + 1] + red[4 * t + 2] + red[4 * t + 3];
                const float val = cload1(sxbuf + r) + dsum * cload1(rdiv + r);
                if (l == LNUM - 1) out[r] = val;  // host-visible at kernel end
                else cstore1(xbuf + r, val);
            }
        }
        if (l < LNUM - 1) {
            FENCE();
            {   // issue next layer's phase-A weights (6 loads/lane)
                const float* keyn = key + (size_t)(l + 1) * 3 * EDIM * EDIM;
                const float4* qA = (const float4*)(keyn + ((size_t)gw << 10));
                pA0 = qA[lane]; pA1 = qA[lane + 64]; pA2 = qA[lane + 128]; pA3 = qA[lane + 192];
                const float4* qR =
                    (const float4*)(keyn + ((size_t)(2048 + rrow) << 10) + (rh << 9));
                rA0 = qR[lane]; rA1 = qR[lane + 64];
            }
            gbar<6>(grp, flags, bi);
        }
    }
}

extern "C" void kernel_launch(void* const* d_in, const int* in_sizes, int n_in,
                              void* d_out, int out_size, void* d_ws, size_t ws_size,
                              hipStream_t stream) {
    const float* x_in = (const float*)d_in[0];
    const float* state = (const float*)d_in[1];
    const float* ln1w = (const float*)d_in[2];
    const float* ln1b = (const float*)d_in[3];
    const float* ln2w = (const float*)d_in[4];
    const float* ln2b = (const float*)d_in[5];
    const float* td = (const float*)d_in[6];
    const float* tf = (const float*)d_in[7];
    const float* key = (const float*)d_in[8];
    const float* ow = (const float*)d_in[9];
    const float* mixk = (const float*)d_in[10];
    const float* mixv = (const float*)d_in[11];
    const float* mixr = (const float*)d_in[12];
    const float* mixkf = (const float*)d_in[13];
    const float* mixrf = (const float*)d_in[14];
    const float* kffn = (const float*)d_in[15];
    const float* rffn = (const float*)d_in[16];
    const float* vffn = (const float*)d_in[17];

    float* out = (float*)d_out;
    float* ws = (float*)d_ws;

    // Barrier state at 48 KB: 8 padded group counters (64 B lines), then
    // 256 per-block release flag lines (64 B each) at +4 KB.
    unsigned* bar = (unsigned*)((char*)d_ws + 48 * 1024);
    unsigned* grp = bar;             // grp[g<<4], g=0..7
    unsigned* flags = bar + 1024;    // flags[b<<4], b=0..255 (16 KB)

    hipMemsetAsync(bar, 0, 24 * 1024, stream);  // deterministic per replay
    rwkv_persistent<<<NB, NT, 0, stream>>>(x_in, state, ln1w, ln1b, ln2w, ln2b, td, tf,
                                           key, ow, mixk, mixv, mixr, mixkf, mixrf,
                                           kffn, rffn, vffn, out, ws, grp, flags);
}

// Round 10
// 520.003 us; speedup vs baseline: 4.9205x; 1.0337x over previous
//
#include <hip/hip_runtime.h>

#define EDIM 1024
#define LNUM 24
#define FDIM 4096
#define NB 256   // persistent blocks, 1 per CU
#define NT 512   // 8 waves per block

__device__ __forceinline__ float wave_sum(float v) {
#pragma unroll
    for (int off = 32; off > 0; off >>= 1) v += __shfl_xor(v, off, 64);
    return v;
}

// Coherent (MALL-visible) accessors for cross-block data. No fences anywhere.
__device__ __forceinline__ float2 cload2(const float* p) {
    double d = __hip_atomic_load((const double*)p, __ATOMIC_RELAXED,
                                 __HIP_MEMORY_SCOPE_AGENT);
    float2 r;
    __builtin_memcpy(&r, &d, 8);
    return r;
}
__device__ __forceinline__ void cstore1(float* p, float v) {
    __hip_atomic_store(p, v, __ATOMIC_RELAXED, __HIP_MEMORY_SCOPE_AGENT);
}
__device__ __forceinline__ void cstore2(float* p, float2 v) {
    double d;
    __builtin_memcpy(&d, &v, 8);
    __hip_atomic_store((double*)p, d, __ATOMIC_RELAXED, __HIP_MEMORY_SCOPE_AGENT);
}

// Pin ordering: stores above, prefetch loads below (needed for counted vmcnt).
#define FENCE()                                  \
    do {                                         \
        asm volatile("" ::: "memory");           \
        __builtin_amdgcn_sched_barrier(0);       \
    } while (0)

// Intra-block barrier that does NOT drain vmcnt.
__device__ __forceinline__ void lbar() {
    asm volatile("s_waitcnt lgkmcnt(0)" ::: "memory");
    __builtin_amdgcn_sched_barrier(0);
    __builtin_amdgcn_s_barrier();
    asm volatile("" ::: "memory");
    __builtin_amdgcn_sched_barrier(0);
}

// Device-wide barrier, counted vmcnt. Arrival: 8 group lines x 32 atomics.
// Group-lasts spin (no sleep) on the 8 group lines; release via per-block
// private flag lines (1 poller per line).
template <int P>
__device__ __forceinline__ void gbar(unsigned* grp, unsigned* flags, unsigned& bi) {
    asm volatile("s_waitcnt vmcnt(%0) lgkmcnt(0)" ::"i"(P) : "memory");
    __builtin_amdgcn_sched_barrier(0);
    __builtin_amdgcn_s_barrier();  // all waves of block: stores drained
    const unsigned bi1 = bi + 1u;
    if (threadIdx.x == 0) {
        const int g = blockIdx.x & 7;
        unsigned o = __hip_atomic_fetch_add(&grp[g << 4], 1u, __ATOMIC_RELAXED,
                                            __HIP_MEMORY_SCOPE_AGENT);
        if ((o & 31u) == 31u) {  // group-last for this epoch
            const unsigned tgt = 32u * bi1;
            int guard = 0;
            for (;;) {
                unsigned mn = 0xffffffffu;
#pragma unroll
                for (int i = 0; i < 8; ++i) {
                    unsigned v = __hip_atomic_load(&grp[i << 4], __ATOMIC_RELAXED,
                                                   __HIP_MEMORY_SCOPE_AGENT);
                    mn = (v < mn) ? v : mn;
                }
                if (mn >= tgt) break;
                if (++guard > (1 << 20)) break;  // fail-fast bailout
            }
#pragma unroll 8
            for (int j = 0; j < 32; ++j)
                __hip_atomic_store(&flags[(g + 8 * j) << 4], bi1, __ATOMIC_RELAXED,
                                   __HIP_MEMORY_SCOPE_AGENT);
        } else {
            int guard = 0;
            while (__hip_atomic_load(&flags[blockIdx.x << 4], __ATOMIC_RELAXED,
                                     __HIP_MEMORY_SCOPE_AGENT) < bi1) {
                __builtin_amdgcn_s_sleep(1);
                if (++guard > (1 << 20)) break;
            }
        }
    }
    __builtin_amdgcn_s_barrier();
    asm volatile("" ::: "memory");
    __builtin_amdgcn_sched_barrier(0);
    ++bi;
}

__device__ __forceinline__ float dot16(const float4& p0, const float4& p1,
                                       const float4& p2, const float4& p3,
                                       const float4& a, const float4& b,
                                       const float4& c, const float4& d) {
    return p0.x * a.x + p0.y * a.y + p0.z * a.z + p0.w * a.w +
           p1.x * b.x + p1.y * b.y + p1.z * b.z + p1.w * b.w +
           p2.x * c.x + p2.y * c.y + p2.z * c.z + p2.w * c.w +
           p3.x * d.x + p3.y * d.y + p3.z * d.z + p3.w * d.w;
}

__device__ __forceinline__ float dot1024_pref(const float4& p0, const float4& p1,
                                              const float4& p2, const float4& p3,
                                              const float* op, int lane) {
    const float4* o = (const float4*)op;
    return wave_sum(dot16(p0, p1, p2, p3, o[lane], o[lane + 64], o[lane + 128],
                          o[lane + 192]));
}

__device__ __forceinline__ float dot512_pref(const float4& p0, const float4& p1,
                                             const float* op, int lane) {
    const float4* o = (const float4*)op;
    const float4 a = o[lane], b4 = o[lane + 64];
    return wave_sum(p0.x * a.x + p0.y * a.y + p0.z * a.z + p0.w * a.w +
                    p1.x * b4.x + p1.y * b4.y + p1.z * b4.z + p1.w * b4.w);
}

__global__ __launch_bounds__(NT, 2) void rwkv_persistent(
    const float* __restrict__ x_in, const float* __restrict__ state,
    const float* __restrict__ ln1w, const float* __restrict__ ln1b,
    const float* __restrict__ ln2w, const float* __restrict__ ln2b,
    const float* __restrict__ td, const float* __restrict__ tf,
    const float* __restrict__ key, const float* __restrict__ ow,
    const float* __restrict__ mixk, const float* __restrict__ mixv,
    const float* __restrict__ mixr, const float* __restrict__ mixkf,
    const float* __restrict__ mixrf, const float* __restrict__ kffn,
    const float* __restrict__ rffn, const float* __restrict__ vffn,
    float* __restrict__ out, float* __restrict__ ws, unsigned* __restrict__ grp,
    unsigned* __restrict__ flags) {
    __shared__ float smem[FDIM + 32];
    float* red = smem + FDIM;  // [0..7]=s, [8..15]=s2

    // Coherent cross-block buffers (partials-forward scheme):
    float* xmat = ws;            // [1024] x_l   (A writes own 4-slice)
    float* sxbuf = ws + 1024;    // [1024] sx_l  (C writes own 4-slice)
    float* kbuf = ws + 2048;     // [1024]
    float* vbuf = ws + 3072;     // [1024]
    float* rkh = ws + 4096;      // [2][1024] k-mat r-row half dots
    float* sxh = ws + 6144;      // [2][1024] ow-row half dots
    float* kfbuf = ws + 8192;    // [4096]
    float* rdh = ws + 12288;     // [2][1024] rfw-row half dots
    float* xpart = ws + 14336;   // [4][1024] vfw-row quarter dots

    float* sa_out = out + EDIM;
    float* sb_out = sa_out + LNUM * EDIM;
    float* sc_out = sb_out + LNUM * EDIM;
    float* sd_out = sc_out + LNUM * EDIM;

    const int t = threadIdx.x;
    const int b = blockIdx.x;
    const int w = t >> 6;
    const int lane = t & 63;
    const int gw = (b << 3) + w;           // 0..2047
    const int rrow = (b << 2) + (w >> 1);  // r-mat / ow / rfw row, halves
    const int rh = w & 1;
    const int drow = (b << 2) + (w >> 2);  // vfw rows, quarters
    const int dch = w & 3;
    const bool slicer = ((t >> 1) == b);   // threads 2b, 2b+1 own elems [4b,4b+4)
    unsigned bi = 0;

    // Prefetch registers (named, never runtime-indexed — rule #20)
    float4 pA0, pA1, pA2, pA3, rA0, rA1;
    float4 pB0, pB1;
    float4 pC10, pC11, pC12, pC13, pC20, pC21, pC22, pC23, rC0, rC1;
    float4 pD0, pD1, pD2, pD3, pD4, pD5, pD6, pD7;

    // Prologue: layer-0 phase-A weights (k/v full row gw; r half-row).
    {
        const float4* qA = (const float4*)(key + ((size_t)gw << 10));
        pA0 = qA[lane]; pA1 = qA[lane + 64]; pA2 = qA[lane + 128]; pA3 = qA[lane + 192];
        const float4* qR =
            (const float4*)(key + ((size_t)(2048 + rrow) << 10) + (rh << 9));
        rA0 = qR[lane]; rA1 = qR[lane + 64];
    }

    for (int l = 0; l < LNUM; ++l) {
        const float* owl = ow + (size_t)l * EDIM * EDIM;
        const float* kfl = kffn + (size_t)l * FDIM * EDIM;
        const float* rfl = rffn + (size_t)l * EDIM * EDIM;
        const float* vfl = vffn + (size_t)l * EDIM * FDIM;
        const int le = l * EDIM;
        const int bsel = (l << 2) & 255;

        // ========== Phase A: assemble x, LN1, k/v/r matvec partials ==========
        {
            float2 xv;
            if (l == 0) {
                xv = ((const float2*)x_in)[t];
            } else {
                // assemble x = sx + (Σ vfw-quarters) * sigmoid-gate  (prev layer D/C)
                const float2 sx2 = cload2(sxbuf + 2 * t);
                const float2 xp0 = cload2(xpart + 2 * t);
                const float2 xp1 = cload2(xpart + 1024 + 2 * t);
                const float2 xp2 = cload2(xpart + 2048 + 2 * t);
                const float2 xp3 = cload2(xpart + 3072 + 2 * t);
                const float2 rd0 = cload2(rdh + 2 * t);
                const float2 rd1 = cload2(rdh + 1024 + 2 * t);
                const float gx = 1.0f / (1.0f + expf(rd0.x + rd1.x));
                const float gy = 1.0f / (1.0f + expf(rd0.y + rd1.y));
                xv.x = sx2.x + (xp0.x + xp1.x + xp2.x + xp3.x) * gx;
                xv.y = sx2.y + (xp0.y + xp1.y + xp2.y + xp3.y) * gy;
                if (slicer) cstore2(xmat + 2 * t, xv);  // materialize own slice for C
            }
            float s = xv.x + xv.y, s2 = xv.x * xv.x + xv.y * xv.y;
#pragma unroll
            for (int off = 32; off > 0; off >>= 1) {
                s += __shfl_xor(s, off, 64);
                s2 += __shfl_xor(s2, off, 64);
            }
            if (lane == 0) { red[w] = s; red[8 + w] = s2; }
            lbar();
            float ts = 0.0f, ts2 = 0.0f;
#pragma unroll
            for (int i = 0; i < 8; ++i) { ts += red[i]; ts2 += red[8 + i]; }
            const float mu = ts * (1.0f / 1024.0f);
            const float inv = rsqrtf(ts2 * (1.0f / 1024.0f) - mu * mu + 1e-5f);
            const float2 wv = ((const float2*)(ln1w + le))[t];
            const float2 bv = ((const float2*)(ln1b + le))[t];
            const float2 xn = make_float2((xv.x - mu) * inv * wv.x + bv.x,
                                          (xv.y - mu) * inv * wv.y + bv.y);
            if (b == bsel) ((float2*)(sa_out + le))[t] = xn;  // sa
            const float2 sav = ((const float2*)(state + le))[t];
            const float2 mk = ((const float2*)(mixk + le))[t];
            const float2 mv = ((const float2*)(mixv + le))[t];
            const float2 mr = ((const float2*)(mixr + le))[t];
            ((float2*)smem)[t] = make_float2(xn.x + mk.x * sav.x, xn.y + mk.y * sav.y);
            ((float2*)(smem + 1024))[t] =
                make_float2(xn.x + mv.x * sav.x, xn.y + mv.y * sav.y);
            ((float2*)(smem + 2048))[t] =
                make_float2(xn.x + mr.x * sav.x, xn.y + mr.y * sav.y);
            lbar();
            const int mat = gw >> 10;  // 0 -> k row, 1 -> v row (prefetched)
            const float d1 = dot1024_pref(pA0, pA1, pA2, pA3, smem + (mat << 10), lane);
            if (lane == 0) {
                if (mat == 0) cstore1(kbuf + gw, expf(d1));
                else          cstore1(vbuf + gw - 1024, d1);
            }
            const float d2 = dot512_pref(rA0, rA1, smem + 2048 + (rh << 9), lane);
            if (lane == 0) cstore1(rkh + (rh << 10) + rrow, d2);  // half partial
        }
        FENCE();
        {   // window A->B: issue pB (ow half-row) + pC1 (kfw row gw)
            const float4* qB = (const float4*)(owl + ((size_t)rrow << 10) + (rh << 9));
            pB0 = qB[lane]; pB1 = qB[lane + 64];
            const float4* q1 = (const float4*)(kfl + ((size_t)gw << 10));
            pC10 = q1[lane]; pC11 = q1[lane + 64]; pC12 = q1[lane + 128]; pC13 = q1[lane + 192];
        }
        gbar<6>(grp, flags, bi);

        // ========== Phase B: WKV + ow matvec half-partials ==========
        {
            const float2 k2 = cload2(kbuf + 2 * t);
            const float2 v2 = cload2(vbuf + 2 * t);
            const float2 r0 = cload2(rkh + 2 * t);
            const float2 r1 = cload2(rkh + 1024 + 2 * t);
            const float2 r2 = make_float2(expf(r0.x + r1.x) + 1.0f,
                                          expf(r0.y + r1.y) + 1.0f);
            const float2 tf2 = ((const float2*)(tf + le))[t];
            const float2 sb2 = ((const float2*)(state + 1 * LNUM * EDIM + le))[t];
            const float2 sc2 = ((const float2*)(state + 2 * LNUM * EDIM + le))[t];
            const float g0 =
                (sb2.x + tf2.x * k2.x * v2.x) / (sc2.x * r2.x + tf2.x * k2.x * r2.x);
            const float g1 =
                (sb2.y + tf2.y * k2.y * v2.y) / (sc2.y * r2.y + tf2.y * k2.y * r2.y);
            ((float2*)smem)[t] = make_float2(g0, g1);
            if (b == bsel + 1) {
                const float2 td2 = ((const float2*)(td + le))[t];
                ((float2*)(sb_out + le))[t] =
                    make_float2(sb2.x * td2.x + k2.x * v2.x, sb2.y * td2.y + k2.y * v2.y);
                ((float2*)(sc_out + le))[t] =
                    make_float2(sc2.x * td2.x + k2.x, sc2.y * td2.y + k2.y);
            }
            lbar();
            const float pd = dot512_pref(pB0, pB1, smem + (rh << 9), lane);
            if (lane == 0) cstore1(sxh + (rh << 10) + rrow, pd);  // half partial
        }
        FENCE();
        {   // window B->C: issue pC2 (kfw row gw+2048) + rC (rfw half-row)
            const float4* q2 = (const float4*)(kfl + ((size_t)(gw + 2048) << 10));
            pC20 = q2[lane]; pC21 = q2[lane + 64]; pC22 = q2[lane + 128]; pC23 = q2[lane + 192];
            const float4* qR = (const float4*)(rfl + ((size_t)rrow << 10) + (rh << 9));
            rC0 = qR[lane]; rC1 = qR[lane + 64];
        }
        gbar<6>(grp, flags, bi);

        // ========== Phase C: assemble sx, LN2, kfw/rfw matvec partials ==========
        {
            float2 xl;
            if (l == 0) xl = ((const float2*)x_in)[t];
            else        xl = cload2(xmat + 2 * t);
            const float2 h0 = cload2(sxh + 2 * t);
            const float2 h1 = cload2(sxh + 1024 + 2 * t);
            const float2 sxv = make_float2(xl.x + h0.x + h1.x, xl.y + h0.y + h1.y);
            if (slicer) cstore2(sxbuf + 2 * t, sxv);  // materialize own slice
            float s = sxv.x + sxv.y, s2 = sxv.x * sxv.x + sxv.y * sxv.y;
#pragma unroll
            for (int off = 32; off > 0; off >>= 1) {
                s += __shfl_xor(s, off, 64);
                s2 += __shfl_xor(s2, off, 64);
            }
            if (lane == 0) { red[w] = s; red[8 + w] = s2; }
            lbar();
            float ts = 0.0f, ts2 = 0.0f;
#pragma unroll
            for (int i = 0; i < 8; ++i) { ts += red[i]; ts2 += red[8 + i]; }
            const float mu = ts * (1.0f / 1024.0f);
            const float inv = rsqrtf(ts2 * (1.0f / 1024.0f) - mu * mu + 1e-5f);
            const float2 wv = ((const float2*)(ln2w + le))[t];
            const float2 bv = ((const float2*)(ln2b + le))[t];
            const float2 x2 = make_float2((sxv.x - mu) * inv * wv.x + bv.x,
                                          (sxv.y - mu) * inv * wv.y + bv.y);
            if (b == bsel + 2) ((float2*)(sd_out + le))[t] = x2;  // sd
            const float2 sdv = ((const float2*)(state + 3 * LNUM * EDIM + le))[t];
            const float2 mkf = ((const float2*)(mixkf + le))[t];
            const float2 mrf = ((const float2*)(mixrf + le))[t];
            ((float2*)smem)[t] = make_float2(x2.x + mkf.x * sdv.x, x2.y + mkf.y * sdv.y);
            ((float2*)(smem + 1024))[t] =
                make_float2(x2.x + mrf.x * sdv.x, x2.y + mrf.y * sdv.y);
            lbar();
            const float d1 = dot1024_pref(pC10, pC11, pC12, pC13, smem, lane);
            if (lane == 0) { const float rl = fmaxf(d1, 0.0f); cstore1(kfbuf + gw, rl * rl); }
            const float d2 = dot1024_pref(pC20, pC21, pC22, pC23, smem, lane);
            if (lane == 0) { const float rl = fmaxf(d2, 0.0f); cstore1(kfbuf + gw + 2048, rl * rl); }
            const float d3 = dot512_pref(rC0, rC1, smem + 1024 + (rh << 9), lane);
            if (lane == 0) cstore1(rdh + (rh << 10) + rrow, d3);  // half partial
        }
        FENCE();
        {   // window C->D: issue both vfw chunk-units
            const float4* q1 = (const float4*)(vfl + ((size_t)drow << 12) + (dch << 10));
            pD0 = q1[lane]; pD1 = q1[lane + 64]; pD2 = q1[lane + 128]; pD3 = q1[lane + 192];
            const float4* q2 =
                (const float4*)(vfl + ((size_t)(drow + 2) << 12) + (dch << 10));
            pD4 = q2[lane]; pD5 = q2[lane + 64]; pD6 = q2[lane + 128]; pD7 = q2[lane + 192];
        }
        gbar<8>(grp, flags, bi);

        // ========== Phase D: vfw matvec quarter-partials ==========
        {
            const double* kfd = (const double*)kfbuf;
#pragma unroll
            for (int j = 0; j < 4; ++j)
                ((double*)smem)[t + j * 512] = __hip_atomic_load(
                    kfd + t + j * 512, __ATOMIC_RELAXED, __HIP_MEMORY_SCOPE_AGENT);
            lbar();
            const float pd0 = dot1024_pref(pD0, pD1, pD2, pD3, smem + (dch << 10), lane);
            const float pd1 = dot1024_pref(pD4, pD5, pD6, pD7, smem + (dch << 10), lane);
            if (lane == 0) {
                cstore1(xpart + (dch << 10) + drow, pd0);
                cstore1(xpart + (dch << 10) + drow + 2, pd1);
            }
        }
        if (l < LNUM - 1) {
            FENCE();
            {   // window D->A': next layer's phase-A weights
                const float* keyn = key + (size_t)(l + 1) * 3 * EDIM * EDIM;
                const float4* qA = (const float4*)(keyn + ((size_t)gw << 10));
                pA0 = qA[lane]; pA1 = qA[lane + 64]; pA2 = qA[lane + 128]; pA3 = qA[lane + 192];
                const float4* qR =
                    (const float4*)(keyn + ((size_t)(2048 + rrow) << 10) + (rh << 9));
                rA0 = qR[lane]; rA1 = qR[lane + 64];
            }
            gbar<6>(grp, flags, bi);
        }
    }

    // ========== Epilogue: assemble final x' and write out[0:1024] ==========
    FENCE();
    gbar<0>(grp, flags, bi);
    if (slicer) {
        const float2 sx2 = cload2(sxbuf + 2 * t);
        const float2 xp0 = cload2(xpart + 2 * t);
        const float2 xp1 = cload2(xpart + 1024 + 2 * t);
        const float2 xp2 = cload2(xpart + 2048 + 2 * t);
        const float2 xp3 = cload2(xpart + 3072 + 2 * t);
        const float2 rd0 = cload2(rdh + 2 * t);
        const float2 rd1 = cload2(rdh + 1024 + 2 * t);
        const float gx = 1.0f / (1.0f + expf(rd0.x + rd1.x));
        const float gy = 1.0f / (1.0f + expf(rd0.y + rd1.y));
        out[2 * t] = sx2.x + (xp0.x + xp1.x + xp2.x + xp3.x) * gx;
        out[2 * t + 1] = sx2.y + (xp0.y + xp1.y + xp2.y + xp3.y) * gy;
    }
}

extern "C" void kernel_launch(void* const* d_in, const int* in_sizes, int n_in,
                              void* d_out, int out_size, void* d_ws, size_t ws_size,
                              hipStream_t stream) {
    const float* x_in = (const float*)d_in[0];
    const float* state = (const float*)d_in[1];
    const float* ln1w = (const float*)d_in[2];
    const float* ln1b = (const float*)d_in[3];
    const float* ln2w = (const float*)d_in[4];
    const float* ln2b = (const float*)d_in[5];
    const float* td = (const float*)d_in[6];
    const float* tf = (const float*)d_in[7];
    const float* key = (const float*)d_in[8];
    const float* ow = (const float*)d_in[9];
    const float* mixk = (const float*)d_in[10];
    const float* mixv = (const float*)d_in[11];
    const float* mixr = (const float*)d_in[12];
    const float* mixkf = (const float*)d_in[13];
    const float* mixrf = (const float*)d_in[14];
    const float* kffn = (const float*)d_in[15];
    const float* rffn = (const float*)d_in[16];
    const float* vffn = (const float*)d_in[17];

    float* out = (float*)d_out;
    float* ws = (float*)d_ws;

    // Vector region: 18432 floats = 72 KB. Barrier state at 96 KB:
    // 8 padded group counters + 256 per-block flag lines (64 B each).
    unsigned* bar = (unsigned*)((char*)d_ws + 96 * 1024);
    unsigned* grp = bar;           // grp[g<<4], g=0..7
    unsigned* flags = bar + 1024;  // flags[b<<4], b=0..255 (16 KB)

    hipMemsetAsync(bar, 0, 24 * 1024, stream);  // deterministic per replay
    rwkv_persistent<<<NB, NT, 0, stream>>>(x_in, state, ln1w, ln1b, ln2w, ln2b, td, tf,
                                           key, ow, mixk, mixv, mixr, mixkf, mixrf,
                                           kffn, rffn, vffn, out, ws, grp, flags);
}